// Round 5
// baseline (363.404 us; speedup 1.0000x reference)
//
#include <hip/hip_runtime.h>

typedef unsigned short u16;
typedef unsigned int u32;
typedef unsigned long long u64;
typedef __attribute__((ext_vector_type(8))) short bf16x8;
typedef __attribute__((ext_vector_type(4))) float f32x4;
typedef float f32x4u __attribute__((ext_vector_type(4), aligned(4)));

__device__ __forceinline__ float bf2f(u16 u) {
  union { u32 i; float f; } c; c.i = ((u32)u) << 16; return c.f;
}
__device__ __forceinline__ u16 f2bf(float f) {
  union { float f; u32 i; } c; c.f = f;
  u32 i = c.i;
  return (u16)((i + 0x7fffu + ((i >> 16) & 1u)) >> 16);
}
// cheap round-half-up bf16 (2 VALU); fine for strictly-positive softmax weights
__device__ __forceinline__ u16 f2bf_fast(float f) {
  union { float f; u32 i; } c; c.f = f;
  return (u16)((c.i + 0x8000u) >> 16);
}
__device__ __forceinline__ void async16(const void* g, void* l) {
  __builtin_amdgcn_global_load_lds((const __attribute__((address_space(1))) void*)g,
                                   (__attribute__((address_space(3))) void*)l, 16, 0, 0);
}

// -------- dtype detect: f32 data -> f32 view is mid-range; bf16-pair data -> 2^~±126 ----
__global__ __launch_bounds__(256) void detect_kernel(const u32* __restrict__ X,
                                                     int* __restrict__ flag) {
  __shared__ int part[4];
  const int tid = threadIdx.x, lane = tid & 63, wave = tid >> 6;
  int votes = 0;
  for (int i = tid; i < 4096; i += 256) {
    const u32 u = X[i];
    union { u32 i; float f; } c; c.i = u;
    const float a = fabsf(c.f);
    if (u == 0u || (a > 1e-6f && a < 1e6f)) votes++;
  }
  #pragma unroll
  for (int off = 32; off >= 1; off >>= 1) votes += __shfl_xor(votes, off);
  if (lane == 0) part[wave] = votes;
  __syncthreads();
  if (tid == 0) {
    const int tot = part[0] + part[1] + part[2] + part[3];
    *flag = (tot >= 2048) ? 0 : 1;  // 0 = f32 inputs, 1 = bf16 inputs
  }
}

// ---------------- weight transposes (z picks which): W[K][N] -> WT[N][K] bf16 ----------------
__global__ __launch_bounds__(256) void transpose_kernel(
    const void* __restrict__ W0, const void* __restrict__ W1, const void* __restrict__ W2,
    const void* __restrict__ W3, u16* __restrict__ T0, u16* __restrict__ T1,
    u16* __restrict__ T2, u16* __restrict__ T3, const int* __restrict__ flagp) {
  const int f32m = (*flagp == 0);
  const int z = blockIdx.z;
  const void* W = (z == 0) ? W0 : (z == 1) ? W1 : (z == 2) ? W2 : W3;
  u16* WT = (z == 0) ? T0 : (z == 1) ? T1 : (z == 2) ? T2 : T3;
  __shared__ u16 t[64][65];
  const int tid = threadIdx.x;
  const int tx = tid & 63, ty = tid >> 6;
  const int n0 = blockIdx.x * 64, k0 = blockIdx.y * 64;
  #pragma unroll
  for (int r = ty; r < 64; r += 4) {
    const size_t idx = (size_t)(k0 + r) * 1024 + n0 + tx;
    t[r][tx] = f32m ? f2bf(((const float*)W)[idx]) : ((const u16*)W)[idx];
  }
  __syncthreads();
  #pragma unroll
  for (int r = ty; r < 64; r += 4) WT[(size_t)(n0 + r) * 1024 + k0 + tx] = t[tx][r];
}

// ---------------- bias table: T[h][d+1023], d = k - q in [-1023,1023] ----------------
__global__ __launch_bounds__(256) void bias_table_kernel(const void* __restrict__ rel_bias,
                                                         float* __restrict__ T,
                                                         const int* __restrict__ flagp) {
  const int f32m = (*flagp == 0);
  const int idx = blockIdx.x * 256 + threadIdx.x;
  if (idx >= 16 * 2047) return;
  const int h = idx / 2047;
  const int d = idx % 2047 - 1023;  // relative_position = mem - ctx
  const int rb = (d > 0) ? 16 : 0;
  const int rp = d < 0 ? -d : d;
  int val;
  if (rp < 8) {
    val = rp;
  } else {
    float t = (logf((float)rp * 0.125f) / 2.772588722239781f) * 8.0f;
    val = 8 + (int)t;
    if (val > 15) val = 15;
  }
  const int bi = (rb + val) * 16 + h;
  T[idx] = f32m ? ((const float*)rel_bias)[bi] : bf2f(((const u16*)rel_bias)[bi]);
}

// ---------------- RMSNorm (T5 style: no mean-sub, no bias) -> bf16 ----------------
__global__ __launch_bounds__(256) void rmsnorm_kernel(const void* __restrict__ X,
                                                      const void* __restrict__ W,
                                                      u16* __restrict__ Out,
                                                      const int* __restrict__ flagp) {
  const int f32m = (*flagp == 0);
  __shared__ float part[4];
  const int tid = threadIdx.x, lane = tid & 63, wave = tid >> 6;
  const size_t row = blockIdx.x;
  const int c = tid * 4;
  float x0, x1, x2, x3, w0f, w1f, w2f, w3f;
  if (f32m) {
    const float4 xx = *(const float4*)((const float*)X + row * 1024 + c);
    x0 = xx.x; x1 = xx.y; x2 = xx.z; x3 = xx.w;
    const float4 ww = *(const float4*)((const float*)W + c);
    w0f = ww.x; w1f = ww.y; w2f = ww.z; w3f = ww.w;
  } else {
    const u32* px = (const u32*)((const u16*)X + row * 1024 + c);
    const u32 a0 = px[0], a1 = px[1];
    x0 = bf2f((u16)a0); x1 = bf2f((u16)(a0 >> 16));
    x2 = bf2f((u16)a1); x3 = bf2f((u16)(a1 >> 16));
    const u32* pw = (const u32*)((const u16*)W + c);
    const u32 b0 = pw[0], b1 = pw[1];
    w0f = bf2f((u16)b0); w1f = bf2f((u16)(b0 >> 16));
    w2f = bf2f((u16)b1); w3f = bf2f((u16)(b1 >> 16));
  }
  float ss = x0 * x0 + x1 * x1 + x2 * x2 + x3 * x3;
  #pragma unroll
  for (int off = 32; off >= 1; off >>= 1) ss += __shfl_xor(ss, off);
  if (lane == 0) part[wave] = ss;
  __syncthreads();
  const float tot = part[0] + part[1] + part[2] + part[3];
  const float scale = rsqrtf(tot * (1.0f / 1024.0f) + 1e-6f);
  const u16 o0 = f2bf(x0 * scale * w0f);
  const u16 o1 = f2bf(x1 * scale * w1f);
  const u16 o2 = f2bf(x2 * scale * w2f);
  const u16 o3 = f2bf(x3 * scale * w3f);
  u32* po = (u32*)(Out + row * 1024 + c);
  po[0] = (u32)o0 | ((u32)o1 << 16);
  po[1] = (u32)o2 | ((u32)o3 << 16);
}

// ---------------- shared 128x128x32 bf16 MFMA GEMM core (A[M][K], BT[N][K]) ----------------
__device__ __forceinline__ void gemm_core(const u16* __restrict__ A, const u16* __restrict__ BT,
                                          u16* As, u16* Bs, f32x4 (&acc)[4][4],
                                          int m0, int n0, int K, int lane, int wave) {
  const int srow = lane >> 2, scol = (lane & 3) * 8;
  const int wm = (wave >> 1) * 64, wn = (wave & 1) * 64;
  for (int kt = 0; kt < K; kt += 32) {
    __syncthreads();
    #pragma unroll
    for (int i = 0; i < 2; ++i) {
      const int c = wave * 2 + i;
      async16(A + (size_t)(m0 + c * 16 + srow) * K + kt + scol, As + c * 512);
      async16(BT + (size_t)(n0 + c * 16 + srow) * K + kt + scol, Bs + c * 512);
    }
    __syncthreads();
    bf16x8 af[4], bfr[4];
    #pragma unroll
    for (int mt = 0; mt < 4; ++mt)
      af[mt] = *(const bf16x8*)(As + (wm + mt * 16 + (lane & 15)) * 32 + (lane >> 4) * 8);
    #pragma unroll
    for (int nt = 0; nt < 4; ++nt)
      bfr[nt] = *(const bf16x8*)(Bs + (wn + nt * 16 + (lane & 15)) * 32 + (lane >> 4) * 8);
    #pragma unroll
    for (int mt = 0; mt < 4; ++mt)
      #pragma unroll
      for (int nt = 0; nt < 4; ++nt)
        acc[mt][nt] = __builtin_amdgcn_mfma_f32_16x16x32_bf16(af[mt], bfr[nt], acc[mt][nt], 0, 0, 0);
  }
}

// ---------------- QKV projection GEMM; z selects Q/K/V; scatter epilogues ----------------
__global__ __launch_bounds__(256) void qkv_gemm_kernel(
    const u16* __restrict__ A, const u16* __restrict__ WTq, const u16* __restrict__ WTk,
    const u16* __restrict__ WTv, u16* __restrict__ Qo, u16* __restrict__ Ko,
    u16* __restrict__ Vo, int K) {
  __shared__ __align__(16) u16 As[128 * 32];
  __shared__ __align__(16) u16 Bs[128 * 32];
  const int tid = threadIdx.x, lane = tid & 63, wave = tid >> 6;
  const int m0 = blockIdx.y * 128, n0 = blockIdx.x * 128;
  const int z = blockIdx.z;
  const u16* BT = (z == 0) ? WTq : (z == 1) ? WTk : WTv;

  f32x4 acc[4][4];
  const f32x4 zero = {0.f, 0.f, 0.f, 0.f};
  #pragma unroll
  for (int i = 0; i < 4; ++i)
    #pragma unroll
    for (int j = 0; j < 4; ++j) acc[i][j] = zero;

  gemm_core(A, BT, As, Bs, acc, m0, n0, K, lane, wave);

  u16* Out = (z == 0) ? Qo : (z == 1) ? Ko : Vo;
  const int wm = (wave >> 1) * 64, wn = (wave & 1) * 64;
  #pragma unroll
  for (int mt = 0; mt < 4; ++mt) {
    const int mrow0 = m0 + wm + mt * 16 + (lane >> 4) * 4;
    const int b = mrow0 >> 10;
    const int s0 = mrow0 & 1023;
    #pragma unroll
    for (int nt = 0; nt < 4; ++nt) {
      const int n = n0 + wn + nt * 16 + (lane & 15);
      const int hh = n >> 6, dk = n & 63;
      if (z == 2) {
        // V^T layout: [b,h,dk,s]; 4 consecutive s -> one 8B store
        uint2 pk;
        pk.x = (u32)f2bf(acc[mt][nt][0]) | ((u32)f2bf(acc[mt][nt][1]) << 16);
        pk.y = (u32)f2bf(acc[mt][nt][2]) | ((u32)f2bf(acc[mt][nt][3]) << 16);
        *(uint2*)(Out + (((size_t)(b * 16 + hh)) * 64 + dk) * 1024 + s0) = pk;
      } else {
        // Q/K layout: [b,h,s,dk]
        #pragma unroll
        for (int r = 0; r < 4; ++r)
          Out[(((size_t)(b * 16 + hh)) * 1024 + (s0 + r)) * 64 + dk] = f2bf(acc[mt][nt][r]);
      }
    }
  }
}

// ---------------- output projection GEMM + residual; dtype-aware store ----------------
__global__ __launch_bounds__(256) void out_gemm_kernel(
    const u16* __restrict__ A, const u16* __restrict__ BT, const void* __restrict__ Res,
    void* __restrict__ Out, int N, int K, const int* __restrict__ flagp) {
  const int f32m = (*flagp == 0);
  __shared__ __align__(16) u16 As[128 * 32];
  __shared__ __align__(16) u16 Bs[128 * 32];
  const int tid = threadIdx.x, lane = tid & 63, wave = tid >> 6;
  const int m0 = blockIdx.y * 128, n0 = blockIdx.x * 128;

  f32x4 acc[4][4];
  const f32x4 zero = {0.f, 0.f, 0.f, 0.f};
  #pragma unroll
  for (int i = 0; i < 4; ++i)
    #pragma unroll
    for (int j = 0; j < 4; ++j) acc[i][j] = zero;

  gemm_core(A, BT, As, Bs, acc, m0, n0, K, lane, wave);

  const int wm = (wave >> 1) * 64, wn = (wave & 1) * 64;
  #pragma unroll
  for (int mt = 0; mt < 4; ++mt) {
    const int mrow0 = m0 + wm + mt * 16 + (lane >> 4) * 4;
    #pragma unroll
    for (int nt = 0; nt < 4; ++nt) {
      const int n = n0 + wn + nt * 16 + (lane & 15);
      #pragma unroll
      for (int r = 0; r < 4; ++r) {
        const size_t idx = (size_t)(mrow0 + r) * N + n;
        if (f32m) {
          ((float*)Out)[idx] = ((const float*)Res)[idx] + acc[mt][nt][r];
        } else {
          ((u16*)Out)[idx] = f2bf(bf2f(((const u16*)Res)[idx]) + acc[mt][nt][r]);
        }
      }
    }
  }
}

// ---------------- barrier-free attention: direct-global fragments, wave-private P ----
// Block = 128 q-rows; wave owns 32 q-rows x full k (complete output rows -> no merge,
// no __syncthreads). K/V fragments loaded straight from global (L1/L2-resident; grid
// swizzled so all 8 q-blocks of one bh share an XCD L2). Scores transposed
// (S^T = K.Q^T, C-init = bias) so P packs as b64 into a wave-private XOR-swizzled
// 4KB LDS buffer, read back as b128 B-frags; PV = V^T.P^T; out packs b64 stores.
// Fixed-shift softmax (|s|<~55): p = exp(s), l = sum p.
__global__ __launch_bounds__(256, 2) void attn_kernel(
    const u16* __restrict__ Q, const u16* __restrict__ K, const u16* __restrict__ VT,
    const float* __restrict__ Tb, u16* __restrict__ ctx) {
  __shared__ __align__(16) u16 Ps[4][32 * 64];  // 16KB, wave-private quarters

  const int tid = threadIdx.x, lane = tid & 63, w = tid >> 6;
  const int c = lane & 15, quad = lane >> 4;
  const int id = blockIdx.x;
  const int bh = id & 127, qc = id >> 7;  // same-bh blocks -> same XCD (id%8 == bh%8)
  const int b = bh >> 4, h = bh & 15;
  const int q0 = qc * 128;
  const int qw = q0 + w * 32;  // wave's first q row
  const u16* Kg = K + (size_t)bh * 1024 * 64;
  const u16* Vg = VT + (size_t)bh * 64 * 1024;
  const float* Th = Tb + h * 2047;
  u16* PsW = &Ps[w][0];  // [32 q][64 k] u16, 16B chunks XOR-swizzled by (q&7)

  // hoisted Q^T B-frags: n=c -> q = qw + nt*16 + c ; k-elems = dk = half*32 + quad*8
  bf16x8 qf[2][2];
  {
    const u16* Qg = Q + ((size_t)bh * 1024 + qw) * 64;
    #pragma unroll
    for (int nt = 0; nt < 2; ++nt)
      #pragma unroll
      for (int half = 0; half < 2; ++half)
        qf[nt][half] = *(const bf16x8*)(Qg + (size_t)(nt * 16 + c) * 64 + half * 32 + quad * 8);
  }

  f32x4 oacc[4][2];  // out^T tiles [dk=dt*16..][q=nt*16..]
  const f32x4 zero = {0.f, 0.f, 0.f, 0.f};
  #pragma unroll
  for (int i = 0; i < 4; ++i)
    #pragma unroll
    for (int j = 0; j < 2; ++j) oacc[i][j] = zero;
  float rsum[2] = {0.f, 0.f};

  #pragma unroll 1
  for (int kt = 0; kt < 16; ++kt) {
    const int k0 = kt * 64;
    // K A-frags direct from global: m=c -> k-row = k0+mt*16+c ; k-elems = dk
    bf16x8 kf[4][2];
    #pragma unroll
    for (int mt = 0; mt < 4; ++mt)
      #pragma unroll
      for (int half = 0; half < 2; ++half)
        kf[mt][half] = *(const bf16x8*)(Kg + (size_t)(k0 + mt * 16 + c) * 64 + half * 32 + quad * 8);
    // bias directly into the MFMA C operand: sc[r] = Th[k - q + 1023], 4 consecutive k
    f32x4 sc[4][2];
    const int bb = k0 + quad * 4 - (qw + c) + 1023;
    #pragma unroll
    for (int mt = 0; mt < 4; ++mt)
      #pragma unroll
      for (int nt = 0; nt < 2; ++nt) {
        const f32x4u t = *(const f32x4u*)(Th + bb + mt * 16 - nt * 16);
        sc[mt][nt][0] = t[0]; sc[mt][nt][1] = t[1]; sc[mt][nt][2] = t[2]; sc[mt][nt][3] = t[3];
      }
    // S^T = K.Q^T
    #pragma unroll
    for (int mt = 0; mt < 4; ++mt)
      #pragma unroll
      for (int nt = 0; nt < 2; ++nt) {
        sc[mt][nt] = __builtin_amdgcn_mfma_f32_16x16x32_bf16(kf[mt][0], qf[nt][0], sc[mt][nt], 0, 0, 0);
        sc[mt][nt] = __builtin_amdgcn_mfma_f32_16x16x32_bf16(kf[mt][1], qf[nt][1], sc[mt][nt], 0, 0, 0);
      }
    // exp -> rsum partial -> pack 4 consecutive k as one b64 swizzled LDS write
    #pragma unroll
    for (int mt = 0; mt < 4; ++mt)
      #pragma unroll
      for (int nt = 0; nt < 2; ++nt) {
        const float p0 = __expf(sc[mt][nt][0]), p1 = __expf(sc[mt][nt][1]);
        const float p2 = __expf(sc[mt][nt][2]), p3 = __expf(sc[mt][nt][3]);
        rsum[nt] += (p0 + p1) + (p2 + p3);
        const u64 pk = (u64)f2bf_fast(p0) | ((u64)f2bf_fast(p1) << 16) |
                       ((u64)f2bf_fast(p2) << 32) | ((u64)f2bf_fast(p3) << 48);
        const int ch = (mt * 2 + (quad >> 1)) ^ (c & 7);
        *(u64*)(PsW + (nt * 16 + c) * 64 + ch * 8 + (quad & 1) * 4) = pk;
      }
    // V A-frags direct from global (issue before the LDS fence; they fly during it)
    bf16x8 vf[4][2];
    #pragma unroll
    for (int dt = 0; dt < 4; ++dt)
      #pragma unroll
      for (int kk = 0; kk < 2; ++kk)
        vf[dt][kk] = *(const bf16x8*)(Vg + (size_t)(dt * 16 + c) * 1024 + k0 + kk * 32 + quad * 8);
    __asm__ volatile("s_waitcnt lgkmcnt(0)" ::: "memory");  // own P writes visible
    // P^T B-frags: n=c -> q ; k-elems = kk*32 + quad*8
    bf16x8 pf[2][2];
    #pragma unroll
    for (int nt = 0; nt < 2; ++nt)
      #pragma unroll
      for (int kk = 0; kk < 2; ++kk) {
        const int ch = (kk * 4 + quad) ^ (c & 7);
        pf[nt][kk] = *(const bf16x8*)(PsW + (nt * 16 + c) * 64 + ch * 8);
      }
    // out^T += V^T . P^T
    #pragma unroll
    for (int dt = 0; dt < 4; ++dt)
      #pragma unroll
      for (int nt = 0; nt < 2; ++nt) {
        oacc[dt][nt] = __builtin_amdgcn_mfma_f32_16x16x32_bf16(vf[dt][0], pf[nt][0], oacc[dt][nt], 0, 0, 0);
        oacc[dt][nt] = __builtin_amdgcn_mfma_f32_16x16x32_bf16(vf[dt][1], pf[nt][1], oacc[dt][nt], 0, 0, 0);
      }
  }

  // fold quads: lanes (c, c+16, c+32, c+48) hold disjoint k-partitions of q-row c
  #pragma unroll
  for (int nt = 0; nt < 2; ++nt) {
    rsum[nt] += __shfl_xor(rsum[nt], 16);
    rsum[nt] += __shfl_xor(rsum[nt], 32);
  }

  #pragma unroll
  for (int nt = 0; nt < 2; ++nt) {
    const float inv = 1.0f / rsum[nt];
    const int q = qw + nt * 16 + c;
    #pragma unroll
    for (int dt = 0; dt < 4; ++dt) {
      const u64 pk = (u64)f2bf(oacc[dt][nt][0] * inv) | ((u64)f2bf(oacc[dt][nt][1] * inv) << 16) |
                     ((u64)f2bf(oacc[dt][nt][2] * inv) << 32) | ((u64)f2bf(oacc[dt][nt][3] * inv) << 48);
      // ctx layout: [b, s, h, dk]; lane holds 4 consecutive dk = dt*16 + quad*4 + r
      *(u64*)(ctx + (((size_t)b * 1024 + q) * 16 + h) * 64 + dt * 16 + quad * 4) = pk;
    }
  }
}

extern "C" void kernel_launch(void* const* d_in, const int* in_sizes, int n_in,
                              void* d_out, int out_size, void* d_ws, size_t ws_size,
                              hipStream_t stream) {
  const void* hidden = d_in[0];
  const void* lnw = d_in[1];
  const void* wq = d_in[2];
  const void* wk = d_in[3];
  const void* wv = d_in[4];
  const void* wo = d_in[5];
  const void* relb = d_in[6];
  char* ws = (char*)d_ws;

  u16* normed = (u16*)(ws);                        // 16 MB; reused as ctx after QKV
  u16* Qb = (u16*)(ws + ((size_t)16 << 20));       // 16 MB
  u16* Kb = (u16*)(ws + ((size_t)32 << 20));       // 16 MB
  u16* VTb = (u16*)(ws + ((size_t)48 << 20));      // 16 MB
  u16* wtq = (u16*)(ws + ((size_t)64 << 20));
  u16* wtk = (u16*)(ws + ((size_t)64 << 20) + (2 << 20));
  u16* wtv = (u16*)(ws + ((size_t)64 << 20) + (4 << 20));
  u16* wto = (u16*)(ws + ((size_t)64 << 20) + (6 << 20));
  float* Tb = (float*)(ws + ((size_t)64 << 20) + (8 << 20));  // 131 KB
  int* flag = (int*)(ws + ((size_t)64 << 20) + (9 << 20));

  dim3 b256(256);
  detect_kernel<<<dim3(1), b256, 0, stream>>>((const u32*)hidden, flag);
  transpose_kernel<<<dim3(16, 16, 4), b256, 0, stream>>>(wq, wk, wv, wo, wtq, wtk, wtv, wto, flag);
  bias_table_kernel<<<dim3(128), b256, 0, stream>>>(relb, Tb, flag);
  rmsnorm_kernel<<<dim3(8192), b256, 0, stream>>>(hidden, lnw, normed, flag);
  qkv_gemm_kernel<<<dim3(8, 64, 3), b256, 0, stream>>>(normed, wtq, wtk, wtv, Qb, Kb, VTb, 1024);
  attn_kernel<<<dim3(1024), b256, 0, stream>>>(Qb, Kb, VTb, Tb, normed);
  out_gemm_kernel<<<dim3(8, 64), b256, 0, stream>>>(normed, wto, hidden, d_out, 1024, 1024, flag);
}

// Round 6
// 303.032 us; speedup vs baseline: 1.1992x; 1.1992x over previous
//
#include <hip/hip_runtime.h>

typedef unsigned short u16;
typedef unsigned int u32;
typedef unsigned long long u64;
typedef __attribute__((ext_vector_type(8))) short bf16x8;
typedef __attribute__((ext_vector_type(4))) float f32x4;
typedef float f32x4u __attribute__((ext_vector_type(4), aligned(4)));

__device__ __forceinline__ float bf2f(u16 u) {
  union { u32 i; float f; } c; c.i = ((u32)u) << 16; return c.f;
}
__device__ __forceinline__ u16 f2bf(float f) {
  union { float f; u32 i; } c; c.f = f;
  u32 i = c.i;
  return (u16)((i + 0x7fffu + ((i >> 16) & 1u)) >> 16);
}
// cheap round-half-up bf16 (2 VALU); fine for strictly-positive softmax weights
__device__ __forceinline__ u16 f2bf_fast(float f) {
  union { float f; u32 i; } c; c.f = f;
  return (u16)((c.i + 0x8000u) >> 16);
}
__device__ __forceinline__ void async16(const void* g, void* l) {
  __builtin_amdgcn_global_load_lds((const __attribute__((address_space(1))) void*)g,
                                   (__attribute__((address_space(3))) void*)l, 16, 0, 0);
}

// -------- dtype detect: f32 data -> f32 view is mid-range; bf16-pair data -> 2^~±126 ----
__global__ __launch_bounds__(256) void detect_kernel(const u32* __restrict__ X,
                                                     int* __restrict__ flag) {
  __shared__ int part[4];
  const int tid = threadIdx.x, lane = tid & 63, wave = tid >> 6;
  int votes = 0;
  for (int i = tid; i < 4096; i += 256) {
    const u32 u = X[i];
    union { u32 i; float f; } c; c.i = u;
    const float a = fabsf(c.f);
    if (u == 0u || (a > 1e-6f && a < 1e6f)) votes++;
  }
  #pragma unroll
  for (int off = 32; off >= 1; off >>= 1) votes += __shfl_xor(votes, off);
  if (lane == 0) part[wave] = votes;
  __syncthreads();
  if (tid == 0) {
    const int tot = part[0] + part[1] + part[2] + part[3];
    *flag = (tot >= 2048) ? 0 : 1;  // 0 = f32 inputs, 1 = bf16 inputs
  }
}

// ------- weight transposes (z<4) + bias table (z==4) merged into one launch -------
__global__ __launch_bounds__(256) void prep_kernel(
    const void* __restrict__ W0, const void* __restrict__ W1, const void* __restrict__ W2,
    const void* __restrict__ W3, u16* __restrict__ T0, u16* __restrict__ T1,
    u16* __restrict__ T2, u16* __restrict__ T3, const void* __restrict__ rel_bias,
    float* __restrict__ Tb, const int* __restrict__ flagp) {
  const int f32m = (*flagp == 0);
  const int z = blockIdx.z;
  if (z == 4) {
    const int flat = blockIdx.y * 16 + blockIdx.x;
    const int idx = flat * 256 + threadIdx.x;
    if (idx >= 16 * 2047) return;
    const int h = idx / 2047;
    const int d = idx % 2047 - 1023;  // relative_position = mem - ctx
    const int rb = (d > 0) ? 16 : 0;
    const int rp = d < 0 ? -d : d;
    int val;
    if (rp < 8) {
      val = rp;
    } else {
      float t = (logf((float)rp * 0.125f) / 2.772588722239781f) * 8.0f;
      val = 8 + (int)t;
      if (val > 15) val = 15;
    }
    const int bi = (rb + val) * 16 + h;
    Tb[idx] = f32m ? ((const float*)rel_bias)[bi] : bf2f(((const u16*)rel_bias)[bi]);
    return;
  }
  const void* W = (z == 0) ? W0 : (z == 1) ? W1 : (z == 2) ? W2 : W3;
  u16* WT = (z == 0) ? T0 : (z == 1) ? T1 : (z == 2) ? T2 : T3;
  __shared__ u16 t[64][65];
  const int tid = threadIdx.x;
  const int tx = tid & 63, ty = tid >> 6;
  const int n0 = blockIdx.x * 64, k0 = blockIdx.y * 64;
  #pragma unroll
  for (int r = ty; r < 64; r += 4) {
    const size_t idx = (size_t)(k0 + r) * 1024 + n0 + tx;
    t[r][tx] = f32m ? f2bf(((const float*)W)[idx]) : ((const u16*)W)[idx];
  }
  __syncthreads();
  #pragma unroll
  for (int r = ty; r < 64; r += 4) WT[(size_t)(n0 + r) * 1024 + k0 + tx] = t[tx][r];
}

// ---------------- RMSNorm (T5 style: no mean-sub, no bias) -> bf16 ----------------
__global__ __launch_bounds__(256) void rmsnorm_kernel(const void* __restrict__ X,
                                                      const void* __restrict__ W,
                                                      u16* __restrict__ Out,
                                                      const int* __restrict__ flagp) {
  const int f32m = (*flagp == 0);
  __shared__ float part[4];
  const int tid = threadIdx.x, lane = tid & 63, wave = tid >> 6;
  const size_t row = blockIdx.x;
  const int c = tid * 4;
  float x0, x1, x2, x3, w0f, w1f, w2f, w3f;
  if (f32m) {
    const float4 xx = *(const float4*)((const float*)X + row * 1024 + c);
    x0 = xx.x; x1 = xx.y; x2 = xx.z; x3 = xx.w;
    const float4 ww = *(const float4*)((const float*)W + c);
    w0f = ww.x; w1f = ww.y; w2f = ww.z; w3f = ww.w;
  } else {
    const u32* px = (const u32*)((const u16*)X + row * 1024 + c);
    const u32 a0 = px[0], a1 = px[1];
    x0 = bf2f((u16)a0); x1 = bf2f((u16)(a0 >> 16));
    x2 = bf2f((u16)a1); x3 = bf2f((u16)(a1 >> 16));
    const u32* pw = (const u32*)((const u16*)W + c);
    const u32 b0 = pw[0], b1 = pw[1];
    w0f = bf2f((u16)b0); w1f = bf2f((u16)(b0 >> 16));
    w2f = bf2f((u16)b1); w3f = bf2f((u16)(b1 >> 16));
  }
  float ss = x0 * x0 + x1 * x1 + x2 * x2 + x3 * x3;
  #pragma unroll
  for (int off = 32; off >= 1; off >>= 1) ss += __shfl_xor(ss, off);
  if (lane == 0) part[wave] = ss;
  __syncthreads();
  const float tot = part[0] + part[1] + part[2] + part[3];
  const float scale = rsqrtf(tot * (1.0f / 1024.0f) + 1e-6f);
  const u16 o0 = f2bf(x0 * scale * w0f);
  const u16 o1 = f2bf(x1 * scale * w1f);
  const u16 o2 = f2bf(x2 * scale * w2f);
  const u16 o3 = f2bf(x3 * scale * w3f);
  u32* po = (u32*)(Out + row * 1024 + c);
  po[0] = (u32)o0 | ((u32)o1 << 16);
  po[1] = (u32)o2 | ((u32)o3 << 16);
}

// ------- shared 128x128x32 bf16 MFMA GEMM core (A[M][K], BT[N][K]) -------
// SWAP=false: acc[mt][nt] lane holds (s = m0+wm+mt*16+quad*4+r, n = n0+wn+nt*16+c)
// SWAP=true (operands swapped; frag reg layouts are identical):
//   lane holds (s = m0+wm+mt*16+c, n = n0+wn+nt*16+quad*4+r) -> 4 consecutive n
template <bool SWAP>
__device__ __forceinline__ void gemm_core(const u16* __restrict__ A, const u16* __restrict__ BT,
                                          u16* As, u16* Bs, f32x4 (&acc)[4][4],
                                          int m0, int n0, int K, int lane, int wave) {
  const int srow = lane >> 2, scol = (lane & 3) * 8;
  const int wm = (wave >> 1) * 64, wn = (wave & 1) * 64;
  for (int kt = 0; kt < K; kt += 32) {
    __syncthreads();
    #pragma unroll
    for (int i = 0; i < 2; ++i) {
      const int c = wave * 2 + i;
      async16(A + (size_t)(m0 + c * 16 + srow) * K + kt + scol, As + c * 512);
      async16(BT + (size_t)(n0 + c * 16 + srow) * K + kt + scol, Bs + c * 512);
    }
    __syncthreads();
    bf16x8 af[4], bfr[4];
    #pragma unroll
    for (int mt = 0; mt < 4; ++mt)
      af[mt] = *(const bf16x8*)(As + (wm + mt * 16 + (lane & 15)) * 32 + (lane >> 4) * 8);
    #pragma unroll
    for (int nt = 0; nt < 4; ++nt)
      bfr[nt] = *(const bf16x8*)(Bs + (wn + nt * 16 + (lane & 15)) * 32 + (lane >> 4) * 8);
    #pragma unroll
    for (int mt = 0; mt < 4; ++mt)
      #pragma unroll
      for (int nt = 0; nt < 4; ++nt) {
        if (SWAP)
          acc[mt][nt] = __builtin_amdgcn_mfma_f32_16x16x32_bf16(bfr[nt], af[mt], acc[mt][nt], 0, 0, 0);
        else
          acc[mt][nt] = __builtin_amdgcn_mfma_f32_16x16x32_bf16(af[mt], bfr[nt], acc[mt][nt], 0, 0, 0);
      }
  }
}

// ---------------- QKV projection GEMM; z selects Q/K/V; packed epilogues ----------------
__global__ __launch_bounds__(256) void qkv_gemm_kernel(
    const u16* __restrict__ A, const u16* __restrict__ WTq, const u16* __restrict__ WTk,
    const u16* __restrict__ WTv, u16* __restrict__ Qo, u16* __restrict__ Ko,
    u16* __restrict__ Vo, int K) {
  __shared__ __align__(16) u16 As[128 * 32];
  __shared__ __align__(16) u16 Bs[128 * 32];
  const int tid = threadIdx.x, lane = tid & 63, wave = tid >> 6;
  const int m0 = blockIdx.y * 128, n0 = blockIdx.x * 128;
  const int z = blockIdx.z;
  const u16* BT = (z == 0) ? WTq : (z == 1) ? WTk : WTv;

  f32x4 acc[4][4];
  const f32x4 zero = {0.f, 0.f, 0.f, 0.f};
  #pragma unroll
  for (int i = 0; i < 4; ++i)
    #pragma unroll
    for (int j = 0; j < 4; ++j) acc[i][j] = zero;

  const int wm = (wave >> 1) * 64, wn = (wave & 1) * 64;
  if (z == 2) {
    gemm_core<false>(A, BT, As, Bs, acc, m0, n0, K, lane, wave);
    // V^T layout: [b,h,dk,s]; lane holds 4 consecutive s for fixed (h,dk) -> b64 store
    #pragma unroll
    for (int mt = 0; mt < 4; ++mt) {
      const int mrow0 = m0 + wm + mt * 16 + (lane >> 4) * 4;
      const int b = mrow0 >> 10;
      const int s0 = mrow0 & 1023;
      #pragma unroll
      for (int nt = 0; nt < 4; ++nt) {
        const int n = n0 + wn + nt * 16 + (lane & 15);
        const int hh = n >> 6, dk = n & 63;
        const u64 pk = (u64)f2bf(acc[mt][nt][0]) | ((u64)f2bf(acc[mt][nt][1]) << 16) |
                       ((u64)f2bf(acc[mt][nt][2]) << 32) | ((u64)f2bf(acc[mt][nt][3]) << 48);
        *(u64*)(Vo + (((size_t)(b * 16 + hh)) * 64 + dk) * 1024 + s0) = pk;
      }
    }
  } else {
    gemm_core<true>(A, BT, As, Bs, acc, m0, n0, K, lane, wave);
    u16* Out = (z == 0) ? Qo : Ko;
    // Q/K layout: [b,h,s,dk]; lane holds 4 consecutive dk for fixed s -> b64 store
    #pragma unroll
    for (int mt = 0; mt < 4; ++mt) {
      const int s = m0 + wm + mt * 16 + (lane & 15);
      const int b = s >> 10, ss = s & 1023;
      #pragma unroll
      for (int nt = 0; nt < 4; ++nt) {
        const int n = n0 + wn + nt * 16 + (lane >> 4) * 4;
        const int hh = n >> 6, dk = n & 63;
        const u64 pk = (u64)f2bf(acc[mt][nt][0]) | ((u64)f2bf(acc[mt][nt][1]) << 16) |
                       ((u64)f2bf(acc[mt][nt][2]) << 32) | ((u64)f2bf(acc[mt][nt][3]) << 48);
        *(u64*)(Out + (((size_t)(b * 16 + hh)) * 1024 + ss) * 64 + dk) = pk;
      }
    }
  }
}

// ---------------- output projection GEMM + residual; packed dtype-aware store ----------------
__global__ __launch_bounds__(256) void out_gemm_kernel(
    const u16* __restrict__ A, const u16* __restrict__ BT, const void* __restrict__ Res,
    void* __restrict__ Out, int N, int K, const int* __restrict__ flagp) {
  const int f32m = (*flagp == 0);
  __shared__ __align__(16) u16 As[128 * 32];
  __shared__ __align__(16) u16 Bs[128 * 32];
  const int tid = threadIdx.x, lane = tid & 63, wave = tid >> 6;
  const int m0 = blockIdx.y * 128, n0 = blockIdx.x * 128;

  f32x4 acc[4][4];
  const f32x4 zero = {0.f, 0.f, 0.f, 0.f};
  #pragma unroll
  for (int i = 0; i < 4; ++i)
    #pragma unroll
    for (int j = 0; j < 4; ++j) acc[i][j] = zero;

  gemm_core<true>(A, BT, As, Bs, acc, m0, n0, K, lane, wave);

  const int wm = (wave >> 1) * 64, wn = (wave & 1) * 64;
  #pragma unroll
  for (int mt = 0; mt < 4; ++mt) {
    const int s = m0 + wm + mt * 16 + (lane & 15);
    #pragma unroll
    for (int nt = 0; nt < 4; ++nt) {
      const int n = n0 + wn + nt * 16 + (lane >> 4) * 4;
      const size_t idx = (size_t)s * N + n;
      if (f32m) {
        const float4 rr = *(const float4*)((const float*)Res + idx);
        float4 oo;
        oo.x = rr.x + acc[mt][nt][0]; oo.y = rr.y + acc[mt][nt][1];
        oo.z = rr.z + acc[mt][nt][2]; oo.w = rr.w + acc[mt][nt][3];
        *(float4*)((float*)Out + idx) = oo;
      } else {
        const u64 rr = *(const u64*)((const u16*)Res + idx);
        const u64 pk =
            (u64)f2bf(bf2f((u16)rr) + acc[mt][nt][0]) |
            ((u64)f2bf(bf2f((u16)(rr >> 16)) + acc[mt][nt][1]) << 16) |
            ((u64)f2bf(bf2f((u16)(rr >> 32)) + acc[mt][nt][2]) << 32) |
            ((u64)f2bf(bf2f((u16)(rr >> 48)) + acc[mt][nt][3]) << 48);
        *(u64*)((u16*)Out + idx) = pk;
      }
    }
  }
}

// -------- pipelined flash attention: dbuf LDS staging, 1 barrier/iter, 32 q/wave --------
// Block = 128 q (4 waves x 32 q, complete rows -> no merge). K-tile = 64 k.
// K/V staged cooperatively via global_load_lds into double-buffered LDS; staging for
// tile t+1 issued right after the barrier so the vmcnt(0) drain at the next barrier is
// already satisfied (pipelined K-loop). Scores transposed (S^T = K.Q^T, C-init = bias);
// P packs b64 into wave-private XOR-swizzled LDS, read back b128; out^T = V^T.P^T.
// Fixed-shift softmax (|s|<~55): p = exp(s), l = sum p.
__global__ __launch_bounds__(256, 3) void attn_kernel(
    const u16* __restrict__ Q, const u16* __restrict__ K, const u16* __restrict__ VT,
    const float* __restrict__ Tb, u16* __restrict__ ctx) {
  __shared__ __align__(16) u16 Ks[2][4096];  // [buf][8 groups x 512] (mt,half)
  __shared__ __align__(16) u16 Vs[2][4096];  // [buf][8 groups x 512] (dt,kk)
  __shared__ __align__(16) u16 Ps[4][2048];  // wave-private [32 q][64 k] swizzled

  const int tid = threadIdx.x, lane = tid & 63, w = tid >> 6;
  const int c = lane & 15, quad = lane >> 4;
  const int id = blockIdx.x;
  const int bh = id & 127, qc = id >> 7;  // same-bh blocks -> same XCD (id%8 == bh%8)
  const int b = bh >> 4, h = bh & 15;
  const int qw = qc * 128 + w * 32;  // wave's first q row
  const u16* Kg = K + (size_t)bh * 1024 * 64;
  const u16* Vg = VT + (size_t)bh * 64 * 1024;
  const float* Th = Tb + h * 2047;
  u16* PsW = &Ps[w][0];

  // hoisted Q^T B-frags: q = qw + nt*16 + c ; k-elems dk = half*32 + quad*8
  bf16x8 qf[2][2];
  {
    const u16* Qg = Q + ((size_t)bh * 1024 + qw) * 64;
    #pragma unroll
    for (int nt = 0; nt < 2; ++nt)
      #pragma unroll
      for (int half = 0; half < 2; ++half)
        qf[nt][half] = *(const bf16x8*)(Qg + (size_t)(nt * 16 + c) * 64 + half * 32 + quad * 8);
  }

  f32x4 oacc[4][2];
  const f32x4 zero = {0.f, 0.f, 0.f, 0.f};
  #pragma unroll
  for (int i = 0; i < 4; ++i)
    #pragma unroll
    for (int j = 0; j < 2; ++j) oacc[i][j] = zero;
  float rsum[2] = {0.f, 0.f};

  // cooperative staging: wave w stages K rows mt=w (both halves) and V rows dt=w
  {
    const int k0 = 0;
    #pragma unroll
    for (int i = 0; i < 2; ++i) {
      async16(Kg + (size_t)(k0 + w * 16 + c) * 64 + i * 32 + quad * 8, &Ks[0][(w * 2 + i) * 512]);
      async16(Vg + (size_t)(w * 16 + c) * 1024 + k0 + i * 32 + quad * 8, &Vs[0][(w * 2 + i) * 512]);
    }
  }

  #pragma unroll 1
  for (int kt = 0; kt < 16; ++kt) {
    const int cur = kt & 1;
    __asm__ volatile("s_waitcnt vmcnt(0)" ::: "memory");  // tile kt staged
    __syncthreads();
    if (kt < 15) {  // stage tile kt+1 into the other buffer (overlaps this iter's compute)
      const int k1 = (kt + 1) * 64;
      #pragma unroll
      for (int i = 0; i < 2; ++i) {
        async16(Kg + (size_t)(k1 + w * 16 + c) * 64 + i * 32 + quad * 8,
                &Ks[1 - cur][(w * 2 + i) * 512]);
        async16(Vg + (size_t)(w * 16 + c) * 1024 + k1 + i * 32 + quad * 8,
                &Vs[1 - cur][(w * 2 + i) * 512]);
      }
    }
    const int k0 = kt * 64;
    // bias into MFMA C operand: bias[k][q] = Th[k - q + 1023]
    f32x4 sc[4][2];
    const int bb = k0 + quad * 4 - (qw + c) + 1023;
    #pragma unroll
    for (int mt = 0; mt < 4; ++mt)
      #pragma unroll
      for (int nt = 0; nt < 2; ++nt) {
        const f32x4u t = *(const f32x4u*)(Th + bb + mt * 16 - nt * 16);
        sc[mt][nt][0] = t[0]; sc[mt][nt][1] = t[1]; sc[mt][nt][2] = t[2]; sc[mt][nt][3] = t[3];
      }
    // S^T = K.Q^T
    const u16* Kc = &Ks[cur][0];
    #pragma unroll
    for (int mt = 0; mt < 4; ++mt) {
      const bf16x8 kf0 = *(const bf16x8*)(Kc + (mt * 2 + 0) * 512 + lane * 8);
      const bf16x8 kf1 = *(const bf16x8*)(Kc + (mt * 2 + 1) * 512 + lane * 8);
      #pragma unroll
      for (int nt = 0; nt < 2; ++nt) {
        sc[mt][nt] = __builtin_amdgcn_mfma_f32_16x16x32_bf16(kf0, qf[nt][0], sc[mt][nt], 0, 0, 0);
        sc[mt][nt] = __builtin_amdgcn_mfma_f32_16x16x32_bf16(kf1, qf[nt][1], sc[mt][nt], 0, 0, 0);
      }
    }
    // exp -> rsum partial -> pack 4 consecutive k as one b64 swizzled LDS write
    #pragma unroll
    for (int mt = 0; mt < 4; ++mt)
      #pragma unroll
      for (int nt = 0; nt < 2; ++nt) {
        const float p0 = __expf(sc[mt][nt][0]), p1 = __expf(sc[mt][nt][1]);
        const float p2 = __expf(sc[mt][nt][2]), p3 = __expf(sc[mt][nt][3]);
        rsum[nt] += (p0 + p1) + (p2 + p3);
        const u64 pk = (u64)f2bf_fast(p0) | ((u64)f2bf_fast(p1) << 16) |
                       ((u64)f2bf_fast(p2) << 32) | ((u64)f2bf_fast(p3) << 48);
        const int ch = (mt * 2 + (quad >> 1)) ^ (c & 7);
        *(u64*)(PsW + (nt * 16 + c) * 64 + ch * 8 + (quad & 1) * 4) = pk;
      }
    __asm__ volatile("s_waitcnt lgkmcnt(0)" ::: "memory");  // own P writes visible
    // out^T += V^T . P^T
    const u16* Vc = &Vs[cur][0];
    bf16x8 pf[2][2];
    #pragma unroll
    for (int nt = 0; nt < 2; ++nt)
      #pragma unroll
      for (int kk = 0; kk < 2; ++kk) {
        const int ch = (kk * 4 + quad) ^ (c & 7);
        pf[nt][kk] = *(const bf16x8*)(PsW + (nt * 16 + c) * 64 + ch * 8);
      }
    #pragma unroll
    for (int dt = 0; dt < 4; ++dt) {
      const bf16x8 vf0 = *(const bf16x8*)(Vc + (dt * 2 + 0) * 512 + lane * 8);
      const bf16x8 vf1 = *(const bf16x8*)(Vc + (dt * 2 + 1) * 512 + lane * 8);
      #pragma unroll
      for (int nt = 0; nt < 2; ++nt) {
        oacc[dt][nt] = __builtin_amdgcn_mfma_f32_16x16x32_bf16(vf0, pf[nt][0], oacc[dt][nt], 0, 0, 0);
        oacc[dt][nt] = __builtin_amdgcn_mfma_f32_16x16x32_bf16(vf1, pf[nt][1], oacc[dt][nt], 0, 0, 0);
      }
    }
  }

  // fold quads: lanes (c, c+16, c+32, c+48) hold disjoint k-partitions of q-row c
  #pragma unroll
  for (int nt = 0; nt < 2; ++nt) {
    rsum[nt] += __shfl_xor(rsum[nt], 16);
    rsum[nt] += __shfl_xor(rsum[nt], 32);
  }

  #pragma unroll
  for (int nt = 0; nt < 2; ++nt) {
    const float inv = 1.0f / rsum[nt];
    const int q = qw + nt * 16 + c;
    #pragma unroll
    for (int dt = 0; dt < 4; ++dt) {
      const u64 pk = (u64)f2bf(oacc[dt][nt][0] * inv) | ((u64)f2bf(oacc[dt][nt][1] * inv) << 16) |
                     ((u64)f2bf(oacc[dt][nt][2] * inv) << 32) | ((u64)f2bf(oacc[dt][nt][3] * inv) << 48);
      // ctx layout: [b, s, h, dk]; lane holds 4 consecutive dk = dt*16 + quad*4 + r
      *(u64*)(ctx + (((size_t)b * 1024 + q) * 16 + h) * 64 + dt * 16 + quad * 4) = pk;
    }
  }
}

extern "C" void kernel_launch(void* const* d_in, const int* in_sizes, int n_in,
                              void* d_out, int out_size, void* d_ws, size_t ws_size,
                              hipStream_t stream) {
  const void* hidden = d_in[0];
  const void* lnw = d_in[1];
  const void* wq = d_in[2];
  const void* wk = d_in[3];
  const void* wv = d_in[4];
  const void* wo = d_in[5];
  const void* relb = d_in[6];
  char* ws = (char*)d_ws;

  u16* normed = (u16*)(ws);                        // 16 MB; reused as ctx after QKV
  u16* Qb = (u16*)(ws + ((size_t)16 << 20));       // 16 MB
  u16* Kb = (u16*)(ws + ((size_t)32 << 20));       // 16 MB
  u16* VTb = (u16*)(ws + ((size_t)48 << 20));      // 16 MB
  u16* wtq = (u16*)(ws + ((size_t)64 << 20));
  u16* wtk = (u16*)(ws + ((size_t)64 << 20) + (2 << 20));
  u16* wtv = (u16*)(ws + ((size_t)64 << 20) + (4 << 20));
  u16* wto = (u16*)(ws + ((size_t)64 << 20) + (6 << 20));
  float* Tb = (float*)(ws + ((size_t)64 << 20) + (8 << 20));  // 131 KB
  int* flag = (int*)(ws + ((size_t)64 << 20) + (9 << 20));

  dim3 b256(256);
  detect_kernel<<<dim3(1), b256, 0, stream>>>((const u32*)hidden, flag);
  prep_kernel<<<dim3(16, 16, 5), b256, 0, stream>>>(wq, wk, wv, wo, wtq, wtk, wtv, wto,
                                                    relb, Tb, flag);
  rmsnorm_kernel<<<dim3(8192), b256, 0, stream>>>(hidden, lnw, normed, flag);
  qkv_gemm_kernel<<<dim3(8, 64, 3), b256, 0, stream>>>(normed, wtq, wtk, wtv, Qb, Kb, VTb, 1024);
  attn_kernel<<<dim3(1024), b256, 0, stream>>>(Qb, Kb, VTb, Tb, normed);
  out_gemm_kernel<<<dim3(8, 64), b256, 0, stream>>>(normed, wto, hidden, d_out, 1024, 1024, flag);
}

// Round 7
// 295.589 us; speedup vs baseline: 1.2294x; 1.0252x over previous
//
#include <hip/hip_runtime.h>

typedef unsigned short u16;
typedef unsigned int u32;
typedef unsigned long long u64;
typedef __attribute__((ext_vector_type(8))) short bf16x8;
typedef __attribute__((ext_vector_type(4))) float f32x4;
typedef float f32x4u __attribute__((ext_vector_type(4), aligned(4)));

__device__ __forceinline__ float bf2f(u16 u) {
  union { u32 i; float f; } c; c.i = ((u32)u) << 16; return c.f;
}
__device__ __forceinline__ u16 f2bf(float f) {
  union { float f; u32 i; } c; c.f = f;
  u32 i = c.i;
  return (u16)((i + 0x7fffu + ((i >> 16) & 1u)) >> 16);
}
// cheap round-half-up bf16 (2 VALU); fine for strictly-positive softmax weights
__device__ __forceinline__ u16 f2bf_fast(float f) {
  union { float f; u32 i; } c; c.f = f;
  return (u16)((c.i + 0x8000u) >> 16);
}
__device__ __forceinline__ void async16(const void* g, void* l) {
  __builtin_amdgcn_global_load_lds((const __attribute__((address_space(1))) void*)g,
                                   (__attribute__((address_space(3))) void*)l, 16, 0, 0);
}

// -------- dtype detect: f32 data -> f32 view is mid-range; bf16-pair data -> 2^~±126 ----
__global__ __launch_bounds__(256) void detect_kernel(const u32* __restrict__ X,
                                                     int* __restrict__ flag) {
  __shared__ int part[4];
  const int tid = threadIdx.x, lane = tid & 63, wave = tid >> 6;
  int votes = 0;
  for (int i = tid; i < 4096; i += 256) {
    const u32 u = X[i];
    union { u32 i; float f; } c; c.i = u;
    const float a = fabsf(c.f);
    if (u == 0u || (a > 1e-6f && a < 1e6f)) votes++;
  }
  #pragma unroll
  for (int off = 32; off >= 1; off >>= 1) votes += __shfl_xor(votes, off);
  if (lane == 0) part[wave] = votes;
  __syncthreads();
  if (tid == 0) {
    const int tot = part[0] + part[1] + part[2] + part[3];
    *flag = (tot >= 2048) ? 0 : 1;  // 0 = f32 inputs, 1 = bf16 inputs
  }
}

// ------- weight transposes (z<4) + bias table (z==4) merged into one launch -------
__global__ __launch_bounds__(256) void prep_kernel(
    const void* __restrict__ W0, const void* __restrict__ W1, const void* __restrict__ W2,
    const void* __restrict__ W3, u16* __restrict__ T0, u16* __restrict__ T1,
    u16* __restrict__ T2, u16* __restrict__ T3, const void* __restrict__ rel_bias,
    float* __restrict__ Tb, const int* __restrict__ flagp) {
  const int f32m = (*flagp == 0);
  const int z = blockIdx.z;
  if (z == 4) {
    const int flat = blockIdx.y * 16 + blockIdx.x;
    const int idx = flat * 256 + threadIdx.x;
    if (idx >= 16 * 2047) return;
    const int h = idx / 2047;
    const int d = idx % 2047 - 1023;  // relative_position = mem - ctx
    const int rb = (d > 0) ? 16 : 0;
    const int rp = d < 0 ? -d : d;
    int val;
    if (rp < 8) {
      val = rp;
    } else {
      float t = (logf((float)rp * 0.125f) / 2.772588722239781f) * 8.0f;
      val = 8 + (int)t;
      if (val > 15) val = 15;
    }
    const int bi = (rb + val) * 16 + h;
    Tb[idx] = f32m ? ((const float*)rel_bias)[bi] : bf2f(((const u16*)rel_bias)[bi]);
    return;
  }
  const void* W = (z == 0) ? W0 : (z == 1) ? W1 : (z == 2) ? W2 : W3;
  u16* WT = (z == 0) ? T0 : (z == 1) ? T1 : (z == 2) ? T2 : T3;
  __shared__ u16 t[64][65];
  const int tid = threadIdx.x;
  const int tx = tid & 63, ty = tid >> 6;
  const int n0 = blockIdx.x * 64, k0 = blockIdx.y * 64;
  #pragma unroll
  for (int r = ty; r < 64; r += 4) {
    const size_t idx = (size_t)(k0 + r) * 1024 + n0 + tx;
    t[r][tx] = f32m ? f2bf(((const float*)W)[idx]) : ((const u16*)W)[idx];
  }
  __syncthreads();
  #pragma unroll
  for (int r = ty; r < 64; r += 4) WT[(size_t)(n0 + r) * 1024 + k0 + tx] = t[tx][r];
}

// ---------------- RMSNorm (T5 style: no mean-sub, no bias) -> bf16 ----------------
__global__ __launch_bounds__(256) void rmsnorm_kernel(const void* __restrict__ X,
                                                      const void* __restrict__ W,
                                                      u16* __restrict__ Out,
                                                      const int* __restrict__ flagp) {
  const int f32m = (*flagp == 0);
  __shared__ float part[4];
  const int tid = threadIdx.x, lane = tid & 63, wave = tid >> 6;
  const size_t row = blockIdx.x;
  const int c = tid * 4;
  float x0, x1, x2, x3, w0f, w1f, w2f, w3f;
  if (f32m) {
    const float4 xx = *(const float4*)((const float*)X + row * 1024 + c);
    x0 = xx.x; x1 = xx.y; x2 = xx.z; x3 = xx.w;
    const float4 ww = *(const float4*)((const float*)W + c);
    w0f = ww.x; w1f = ww.y; w2f = ww.z; w3f = ww.w;
  } else {
    const u32* px = (const u32*)((const u16*)X + row * 1024 + c);
    const u32 a0 = px[0], a1 = px[1];
    x0 = bf2f((u16)a0); x1 = bf2f((u16)(a0 >> 16));
    x2 = bf2f((u16)a1); x3 = bf2f((u16)(a1 >> 16));
    const u32* pw = (const u32*)((const u16*)W + c);
    const u32 b0 = pw[0], b1 = pw[1];
    w0f = bf2f((u16)b0); w1f = bf2f((u16)(b0 >> 16));
    w2f = bf2f((u16)b1); w3f = bf2f((u16)(b1 >> 16));
  }
  float ss = x0 * x0 + x1 * x1 + x2 * x2 + x3 * x3;
  #pragma unroll
  for (int off = 32; off >= 1; off >>= 1) ss += __shfl_xor(ss, off);
  if (lane == 0) part[wave] = ss;
  __syncthreads();
  const float tot = part[0] + part[1] + part[2] + part[3];
  const float scale = rsqrtf(tot * (1.0f / 1024.0f) + 1e-6f);
  const u16 o0 = f2bf(x0 * scale * w0f);
  const u16 o1 = f2bf(x1 * scale * w1f);
  const u16 o2 = f2bf(x2 * scale * w2f);
  const u16 o3 = f2bf(x3 * scale * w3f);
  u32* po = (u32*)(Out + row * 1024 + c);
  po[0] = (u32)o0 | ((u32)o1 << 16);
  po[1] = (u32)o2 | ((u32)o3 << 16);
}

// ------- shared 128x128x32 bf16 MFMA GEMM core (A[M][K], BT[N][K]) -------
// SWAP=false: acc[mt][nt] lane holds (s = m0+wm+mt*16+quad*4+r, n = n0+wn+nt*16+c)
// SWAP=true (operands swapped; frag reg layouts are identical):
//   lane holds (s = m0+wm+mt*16+c, n = n0+wn+nt*16+quad*4+r) -> 4 consecutive n
template <bool SWAP>
__device__ __forceinline__ void gemm_core(const u16* __restrict__ A, const u16* __restrict__ BT,
                                          u16* As, u16* Bs, f32x4 (&acc)[4][4],
                                          int m0, int n0, int K, int lane, int wave) {
  const int srow = lane >> 2, scol = (lane & 3) * 8;
  const int wm = (wave >> 1) * 64, wn = (wave & 1) * 64;
  for (int kt = 0; kt < K; kt += 32) {
    __syncthreads();
    #pragma unroll
    for (int i = 0; i < 2; ++i) {
      const int c = wave * 2 + i;
      async16(A + (size_t)(m0 + c * 16 + srow) * K + kt + scol, As + c * 512);
      async16(BT + (size_t)(n0 + c * 16 + srow) * K + kt + scol, Bs + c * 512);
    }
    __syncthreads();
    bf16x8 af[4], bfr[4];
    #pragma unroll
    for (int mt = 0; mt < 4; ++mt)
      af[mt] = *(const bf16x8*)(As + (wm + mt * 16 + (lane & 15)) * 32 + (lane >> 4) * 8);
    #pragma unroll
    for (int nt = 0; nt < 4; ++nt)
      bfr[nt] = *(const bf16x8*)(Bs + (wn + nt * 16 + (lane & 15)) * 32 + (lane >> 4) * 8);
    #pragma unroll
    for (int mt = 0; mt < 4; ++mt)
      #pragma unroll
      for (int nt = 0; nt < 4; ++nt) {
        if (SWAP)
          acc[mt][nt] = __builtin_amdgcn_mfma_f32_16x16x32_bf16(bfr[nt], af[mt], acc[mt][nt], 0, 0, 0);
        else
          acc[mt][nt] = __builtin_amdgcn_mfma_f32_16x16x32_bf16(af[mt], bfr[nt], acc[mt][nt], 0, 0, 0);
      }
  }
}

// ------- fused QKV projection GEMM: B = [WTq;WTk;WTv] = [3072][1024] -------
// XCD-aware swizzle: id = 8*(nb + 24*mhi) + (m&7) -> all 24 n-blocks sharing an
// A row-block run on one XCD (A enters each L2 once); weights are L3-resident.
__global__ __launch_bounds__(256) void qkv_gemm_kernel(
    const u16* __restrict__ A, const u16* __restrict__ WT,
    u16* __restrict__ Qo, u16* __restrict__ Ko, u16* __restrict__ Vo, int K) {
  __shared__ __align__(16) u16 As[128 * 32];
  __shared__ __align__(16) u16 Bs[128 * 32];
  const int tid = threadIdx.x, lane = tid & 63, wave = tid >> 6;
  const int id = blockIdx.x;
  const int xcd = id & 7;
  const int t = id >> 3;
  const int nb = t % 24;
  const int mhi = t / 24;
  const int m0 = (mhi * 8 + xcd) * 128;
  const int n0 = nb * 128;  // in [0,3072)
  const int z = nb >> 3;    // 0=Q 1=K 2=V

  f32x4 acc[4][4];
  const f32x4 zero = {0.f, 0.f, 0.f, 0.f};
  #pragma unroll
  for (int i = 0; i < 4; ++i)
    #pragma unroll
    for (int j = 0; j < 4; ++j) acc[i][j] = zero;

  const int wm = (wave >> 1) * 64, wn = (wave & 1) * 64;
  if (z == 2) {
    gemm_core<false>(A, WT, As, Bs, acc, m0, n0, K, lane, wave);
    // V^T layout: [b,h,dk,s]; lane holds 4 consecutive s for fixed (h,dk) -> b64 store
    #pragma unroll
    for (int mt = 0; mt < 4; ++mt) {
      const int mrow0 = m0 + wm + mt * 16 + (lane >> 4) * 4;
      const int b = mrow0 >> 10;
      const int s0 = mrow0 & 1023;
      #pragma unroll
      for (int nt = 0; nt < 4; ++nt) {
        const int n = (n0 + wn + nt * 16 + (lane & 15)) & 1023;
        const int hh = n >> 6, dk = n & 63;
        const u64 pk = (u64)f2bf(acc[mt][nt][0]) | ((u64)f2bf(acc[mt][nt][1]) << 16) |
                       ((u64)f2bf(acc[mt][nt][2]) << 32) | ((u64)f2bf(acc[mt][nt][3]) << 48);
        *(u64*)(Vo + (((size_t)(b * 16 + hh)) * 64 + dk) * 1024 + s0) = pk;
      }
    }
  } else {
    gemm_core<true>(A, WT, As, Bs, acc, m0, n0, K, lane, wave);
    u16* Out = (z == 0) ? Qo : Ko;
    // Q/K layout: [b,h,s,dk]; lane holds 4 consecutive dk for fixed s -> b64 store
    #pragma unroll
    for (int mt = 0; mt < 4; ++mt) {
      const int s = m0 + wm + mt * 16 + (lane & 15);
      const int b = s >> 10, ss = s & 1023;
      #pragma unroll
      for (int nt = 0; nt < 4; ++nt) {
        const int n = (n0 + wn + nt * 16 + (lane >> 4) * 4) & 1023;
        const int hh = n >> 6, dk = n & 63;
        const u64 pk = (u64)f2bf(acc[mt][nt][0]) | ((u64)f2bf(acc[mt][nt][1]) << 16) |
                       ((u64)f2bf(acc[mt][nt][2]) << 32) | ((u64)f2bf(acc[mt][nt][3]) << 48);
        *(u64*)(Out + (((size_t)(b * 16 + hh)) * 1024 + ss) * 64 + dk) = pk;
      }
    }
  }
}

// ---------------- output projection GEMM + residual; packed dtype-aware store ----------------
// Same XCD-aware swizzle: id = 8*(nb + 8*mhi) + (m&7)
__global__ __launch_bounds__(256) void out_gemm_kernel(
    const u16* __restrict__ A, const u16* __restrict__ BT, const void* __restrict__ Res,
    void* __restrict__ Out, int N, int K, const int* __restrict__ flagp) {
  const int f32m = (*flagp == 0);
  __shared__ __align__(16) u16 As[128 * 32];
  __shared__ __align__(16) u16 Bs[128 * 32];
  const int tid = threadIdx.x, lane = tid & 63, wave = tid >> 6;
  const int id = blockIdx.x;
  const int xcd = id & 7;
  const int t = id >> 3;
  const int nb = t & 7;
  const int mhi = t >> 3;
  const int m0 = (mhi * 8 + xcd) * 128;
  const int n0 = nb * 128;

  f32x4 acc[4][4];
  const f32x4 zero = {0.f, 0.f, 0.f, 0.f};
  #pragma unroll
  for (int i = 0; i < 4; ++i)
    #pragma unroll
    for (int j = 0; j < 4; ++j) acc[i][j] = zero;

  gemm_core<true>(A, BT, As, Bs, acc, m0, n0, K, lane, wave);

  const int wm = (wave >> 1) * 64, wn = (wave & 1) * 64;
  #pragma unroll
  for (int mt = 0; mt < 4; ++mt) {
    const int s = m0 + wm + mt * 16 + (lane & 15);
    #pragma unroll
    for (int nt = 0; nt < 4; ++nt) {
      const int n = n0 + wn + nt * 16 + (lane >> 4) * 4;
      const size_t idx = (size_t)s * N + n;
      if (f32m) {
        const float4 rr = *(const float4*)((const float*)Res + idx);
        float4 oo;
        oo.x = rr.x + acc[mt][nt][0]; oo.y = rr.y + acc[mt][nt][1];
        oo.z = rr.z + acc[mt][nt][2]; oo.w = rr.w + acc[mt][nt][3];
        *(float4*)((float*)Out + idx) = oo;
      } else {
        const u64 rr = *(const u64*)((const u16*)Res + idx);
        const u64 pk =
            (u64)f2bf(bf2f((u16)rr) + acc[mt][nt][0]) |
            ((u64)f2bf(bf2f((u16)(rr >> 16)) + acc[mt][nt][1]) << 16) |
            ((u64)f2bf(bf2f((u16)(rr >> 32)) + acc[mt][nt][2]) << 32) |
            ((u64)f2bf(bf2f((u16)(rr >> 48)) + acc[mt][nt][3]) << 48);
        *(u64*)((u16*)Out + idx) = pk;
      }
    }
  }
}

// -------- pipelined flash attention: dbuf LDS staging, 1 barrier/iter, 32 q/wave --------
// Block = 128 q (4 waves x 32 q, complete rows -> no merge). K-tile = 64 k.
// K/V staged cooperatively via global_load_lds into double-buffered LDS; staging for
// tile t+1 issued right after the barrier so the vmcnt(0) drain at the next barrier is
// already satisfied (pipelined K-loop). Scores transposed (S^T = K.Q^T, C-init = bias);
// P packs b64 into wave-private XOR-swizzled LDS, read back b128; out^T = V^T.P^T.
// Fixed-shift softmax (|s|<~55): p = exp(s), l = sum p.
__global__ __launch_bounds__(256, 3) void attn_kernel(
    const u16* __restrict__ Q, const u16* __restrict__ K, const u16* __restrict__ VT,
    const float* __restrict__ Tb, u16* __restrict__ ctx) {
  __shared__ __align__(16) u16 Ks[2][4096];  // [buf][8 groups x 512] (mt,half)
  __shared__ __align__(16) u16 Vs[2][4096];  // [buf][8 groups x 512] (dt,kk)
  __shared__ __align__(16) u16 Ps[4][2048];  // wave-private [32 q][64 k] swizzled

  const int tid = threadIdx.x, lane = tid & 63, w = tid >> 6;
  const int c = lane & 15, quad = lane >> 4;
  const int id = blockIdx.x;
  const int bh = id & 127, qc = id >> 7;  // same-bh blocks -> same XCD (id%8 == bh%8)
  const int b = bh >> 4, h = bh & 15;
  const int qw = qc * 128 + w * 32;  // wave's first q row
  const u16* Kg = K + (size_t)bh * 1024 * 64;
  const u16* Vg = VT + (size_t)bh * 64 * 1024;
  const float* Th = Tb + h * 2047;
  u16* PsW = &Ps[w][0];

  // hoisted Q^T B-frags: q = qw + nt*16 + c ; k-elems dk = half*32 + quad*8
  bf16x8 qf[2][2];
  {
    const u16* Qg = Q + ((size_t)bh * 1024 + qw) * 64;
    #pragma unroll
    for (int nt = 0; nt < 2; ++nt)
      #pragma unroll
      for (int half = 0; half < 2; ++half)
        qf[nt][half] = *(const bf16x8*)(Qg + (size_t)(nt * 16 + c) * 64 + half * 32 + quad * 8);
  }

  f32x4 oacc[4][2];
  const f32x4 zero = {0.f, 0.f, 0.f, 0.f};
  #pragma unroll
  for (int i = 0; i < 4; ++i)
    #pragma unroll
    for (int j = 0; j < 2; ++j) oacc[i][j] = zero;
  float rsum[2] = {0.f, 0.f};

  // cooperative staging: wave w stages K rows mt=w (both halves) and V rows dt=w
  {
    const int k0 = 0;
    #pragma unroll
    for (int i = 0; i < 2; ++i) {
      async16(Kg + (size_t)(k0 + w * 16 + c) * 64 + i * 32 + quad * 8, &Ks[0][(w * 2 + i) * 512]);
      async16(Vg + (size_t)(w * 16 + c) * 1024 + k0 + i * 32 + quad * 8, &Vs[0][(w * 2 + i) * 512]);
    }
  }

  #pragma unroll 1
  for (int kt = 0; kt < 16; ++kt) {
    const int cur = kt & 1;
    __asm__ volatile("s_waitcnt vmcnt(0)" ::: "memory");  // tile kt staged
    __syncthreads();
    if (kt < 15) {  // stage tile kt+1 into the other buffer (overlaps this iter's compute)
      const int k1 = (kt + 1) * 64;
      #pragma unroll
      for (int i = 0; i < 2; ++i) {
        async16(Kg + (size_t)(k1 + w * 16 + c) * 64 + i * 32 + quad * 8,
                &Ks[1 - cur][(w * 2 + i) * 512]);
        async16(Vg + (size_t)(w * 16 + c) * 1024 + k1 + i * 32 + quad * 8,
                &Vs[1 - cur][(w * 2 + i) * 512]);
      }
    }
    const int k0 = kt * 64;
    // bias into MFMA C operand: bias[k][q] = Th[k - q + 1023]
    f32x4 sc[4][2];
    const int bb = k0 + quad * 4 - (qw + c) + 1023;
    #pragma unroll
    for (int mt = 0; mt < 4; ++mt)
      #pragma unroll
      for (int nt = 0; nt < 2; ++nt) {
        const f32x4u t = *(const f32x4u*)(Th + bb + mt * 16 - nt * 16);
        sc[mt][nt][0] = t[0]; sc[mt][nt][1] = t[1]; sc[mt][nt][2] = t[2]; sc[mt][nt][3] = t[3];
      }
    // S^T = K.Q^T
    const u16* Kc = &Ks[cur][0];
    #pragma unroll
    for (int mt = 0; mt < 4; ++mt) {
      const bf16x8 kf0 = *(const bf16x8*)(Kc + (mt * 2 + 0) * 512 + lane * 8);
      const bf16x8 kf1 = *(const bf16x8*)(Kc + (mt * 2 + 1) * 512 + lane * 8);
      #pragma unroll
      for (int nt = 0; nt < 2; ++nt) {
        sc[mt][nt] = __builtin_amdgcn_mfma_f32_16x16x32_bf16(kf0, qf[nt][0], sc[mt][nt], 0, 0, 0);
        sc[mt][nt] = __builtin_amdgcn_mfma_f32_16x16x32_bf16(kf1, qf[nt][1], sc[mt][nt], 0, 0, 0);
      }
    }
    // exp -> rsum partial -> pack 4 consecutive k as one b64 swizzled LDS write
    #pragma unroll
    for (int mt = 0; mt < 4; ++mt)
      #pragma unroll
      for (int nt = 0; nt < 2; ++nt) {
        const float p0 = __expf(sc[mt][nt][0]), p1 = __expf(sc[mt][nt][1]);
        const float p2 = __expf(sc[mt][nt][2]), p3 = __expf(sc[mt][nt][3]);
        rsum[nt] += (p0 + p1) + (p2 + p3);
        const u64 pk = (u64)f2bf_fast(p0) | ((u64)f2bf_fast(p1) << 16) |
                       ((u64)f2bf_fast(p2) << 32) | ((u64)f2bf_fast(p3) << 48);
        const int ch = (mt * 2 + (quad >> 1)) ^ (c & 7);
        *(u64*)(PsW + (nt * 16 + c) * 64 + ch * 8 + (quad & 1) * 4) = pk;
      }
    __asm__ volatile("s_waitcnt lgkmcnt(0)" ::: "memory");  // own P writes visible
    // out^T += V^T . P^T
    const u16* Vc = &Vs[cur][0];
    bf16x8 pf[2][2];
    #pragma unroll
    for (int nt = 0; nt < 2; ++nt)
      #pragma unroll
      for (int kk = 0; kk < 2; ++kk) {
        const int ch = (kk * 4 + quad) ^ (c & 7);
        pf[nt][kk] = *(const bf16x8*)(PsW + (nt * 16 + c) * 64 + ch * 8);
      }
    #pragma unroll
    for (int dt = 0; dt < 4; ++dt) {
      const bf16x8 vf0 = *(const bf16x8*)(Vc + (dt * 2 + 0) * 512 + lane * 8);
      const bf16x8 vf1 = *(const bf16x8*)(Vc + (dt * 2 + 1) * 512 + lane * 8);
      #pragma unroll
      for (int nt = 0; nt < 2; ++nt) {
        oacc[dt][nt] = __builtin_amdgcn_mfma_f32_16x16x32_bf16(vf0, pf[nt][0], oacc[dt][nt], 0, 0, 0);
        oacc[dt][nt] = __builtin_amdgcn_mfma_f32_16x16x32_bf16(vf1, pf[nt][1], oacc[dt][nt], 0, 0, 0);
      }
    }
  }

  // fold quads: lanes (c, c+16, c+32, c+48) hold disjoint k-partitions of q-row c
  #pragma unroll
  for (int nt = 0; nt < 2; ++nt) {
    rsum[nt] += __shfl_xor(rsum[nt], 16);
    rsum[nt] += __shfl_xor(rsum[nt], 32);
  }

  #pragma unroll
  for (int nt = 0; nt < 2; ++nt) {
    const float inv = 1.0f / rsum[nt];
    const int q = qw + nt * 16 + c;
    #pragma unroll
    for (int dt = 0; dt < 4; ++dt) {
      const u64 pk = (u64)f2bf(oacc[dt][nt][0] * inv) | ((u64)f2bf(oacc[dt][nt][1] * inv) << 16) |
                     ((u64)f2bf(oacc[dt][nt][2] * inv) << 32) | ((u64)f2bf(oacc[dt][nt][3] * inv) << 48);
      // ctx layout: [b, s, h, dk]; lane holds 4 consecutive dk = dt*16 + quad*4 + r
      *(u64*)(ctx + (((size_t)b * 1024 + q) * 16 + h) * 64 + dt * 16 + quad * 4) = pk;
    }
  }
}

extern "C" void kernel_launch(void* const* d_in, const int* in_sizes, int n_in,
                              void* d_out, int out_size, void* d_ws, size_t ws_size,
                              hipStream_t stream) {
  const void* hidden = d_in[0];
  const void* lnw = d_in[1];
  const void* wq = d_in[2];
  const void* wk = d_in[3];
  const void* wv = d_in[4];
  const void* wo = d_in[5];
  const void* relb = d_in[6];
  char* ws = (char*)d_ws;

  u16* normed = (u16*)(ws);                        // 16 MB; reused as ctx after QKV
  u16* Qb = (u16*)(ws + ((size_t)16 << 20));       // 16 MB
  u16* Kb = (u16*)(ws + ((size_t)32 << 20));       // 16 MB
  u16* VTb = (u16*)(ws + ((size_t)48 << 20));      // 16 MB
  u16* wtq = (u16*)(ws + ((size_t)64 << 20));      // [3072][1024] fused B: wtq|wtk|wtv
  u16* wtk = (u16*)(ws + ((size_t)64 << 20) + (2 << 20));
  u16* wtv = (u16*)(ws + ((size_t)64 << 20) + (4 << 20));
  u16* wto = (u16*)(ws + ((size_t)64 << 20) + (6 << 20));
  float* Tb = (float*)(ws + ((size_t)64 << 20) + (8 << 20));  // 131 KB
  int* flag = (int*)(ws + ((size_t)64 << 20) + (9 << 20));

  dim3 b256(256);
  detect_kernel<<<dim3(1), b256, 0, stream>>>((const u32*)hidden, flag);
  prep_kernel<<<dim3(16, 16, 5), b256, 0, stream>>>(wq, wk, wv, wo, wtq, wtk, wtv, wto,
                                                    relb, Tb, flag);
  rmsnorm_kernel<<<dim3(8192), b256, 0, stream>>>(hidden, lnw, normed, flag);
  qkv_gemm_kernel<<<dim3(1536), b256, 0, stream>>>(normed, wtq, Qb, Kb, VTb, 1024);
  attn_kernel<<<dim3(1024), b256, 0, stream>>>(Qb, Kb, VTb, Tb, normed);
  out_gemm_kernel<<<dim3(512), b256, 0, stream>>>(normed, wto, hidden, d_out, 1024, 1024, flag);
}

// Round 8
// 282.021 us; speedup vs baseline: 1.2886x; 1.0481x over previous
//
#include <hip/hip_runtime.h>

typedef unsigned short u16;
typedef unsigned int u32;
typedef unsigned long long u64;
typedef __attribute__((ext_vector_type(8))) short bf16x8;
typedef __attribute__((ext_vector_type(4))) float f32x4;

__device__ __forceinline__ float bf2f(u16 u) {
  union { u32 i; float f; } c; c.i = ((u32)u) << 16; return c.f;
}
__device__ __forceinline__ u16 f2bf(float f) {
  union { float f; u32 i; } c; c.f = f;
  u32 i = c.i;
  return (u16)((i + 0x7fffu + ((i >> 16) & 1u)) >> 16);
}
// pack two floats to two round-half-up bf16 in one u32: add, add, v_perm
__device__ __forceinline__ u32 pkbf(float a, float b) {
  union { float f; u32 i; } ca, cb; ca.f = a; cb.f = b;
  return __builtin_amdgcn_perm(cb.i + 0x8000u, ca.i + 0x8000u, 0x07060302u);
}
__device__ __forceinline__ void async16(const void* g, void* l) {
  __builtin_amdgcn_global_load_lds((const __attribute__((address_space(1))) void*)g,
                                   (__attribute__((address_space(3))) void*)l, 16, 0, 0);
}

// -------- dtype detect: f32 data -> f32 view is mid-range; bf16-pair data -> 2^~±126 ----
__global__ __launch_bounds__(256) void detect_kernel(const u32* __restrict__ X,
                                                     int* __restrict__ flag) {
  __shared__ int part[4];
  const int tid = threadIdx.x, lane = tid & 63, wave = tid >> 6;
  int votes = 0;
  for (int i = tid; i < 4096; i += 256) {
    const u32 u = X[i];
    union { u32 i; float f; } c; c.i = u;
    const float a = fabsf(c.f);
    if (u == 0u || (a > 1e-6f && a < 1e6f)) votes++;
  }
  #pragma unroll
  for (int off = 32; off >= 1; off >>= 1) votes += __shfl_xor(votes, off);
  if (lane == 0) part[wave] = votes;
  __syncthreads();
  if (tid == 0) {
    const int tot = part[0] + part[1] + part[2] + part[3];
    *flag = (tot >= 2048) ? 0 : 1;  // 0 = f32 inputs, 1 = bf16 inputs
  }
}

// ------- weight transposes (z<4) + bias table (z==4) merged into one launch -------
__global__ __launch_bounds__(256) void prep_kernel(
    const void* __restrict__ W0, const void* __restrict__ W1, const void* __restrict__ W2,
    const void* __restrict__ W3, u16* __restrict__ T0, u16* __restrict__ T1,
    u16* __restrict__ T2, u16* __restrict__ T3, const void* __restrict__ rel_bias,
    float* __restrict__ Tb, const int* __restrict__ flagp) {
  const int f32m = (*flagp == 0);
  const int z = blockIdx.z;
  if (z == 4) {
    const int flat = blockIdx.y * 16 + blockIdx.x;
    const int idx = flat * 256 + threadIdx.x;
    if (idx >= 16 * 2047) return;
    const int h = idx / 2047;
    const int d = idx % 2047 - 1023;  // relative_position = mem - ctx
    const int rb = (d > 0) ? 16 : 0;
    const int rp = d < 0 ? -d : d;
    int val;
    if (rp < 8) {
      val = rp;
    } else {
      float t = (logf((float)rp * 0.125f) / 2.772588722239781f) * 8.0f;
      val = 8 + (int)t;
      if (val > 15) val = 15;
    }
    const int bi = (rb + val) * 16 + h;
    Tb[idx] = f32m ? ((const float*)rel_bias)[bi] : bf2f(((const u16*)rel_bias)[bi]);
    return;
  }
  const void* W = (z == 0) ? W0 : (z == 1) ? W1 : (z == 2) ? W2 : W3;
  u16* WT = (z == 0) ? T0 : (z == 1) ? T1 : (z == 2) ? T2 : T3;
  __shared__ u16 t[64][65];
  const int tid = threadIdx.x;
  const int tx = tid & 63, ty = tid >> 6;
  const int n0 = blockIdx.x * 64, k0 = blockIdx.y * 64;
  #pragma unroll
  for (int r = ty; r < 64; r += 4) {
    const size_t idx = (size_t)(k0 + r) * 1024 + n0 + tx;
    t[r][tx] = f32m ? f2bf(((const float*)W)[idx]) : ((const u16*)W)[idx];
  }
  __syncthreads();
  #pragma unroll
  for (int r = ty; r < 64; r += 4) WT[(size_t)(n0 + r) * 1024 + k0 + tx] = t[tx][r];
}

// ---------------- RMSNorm (T5 style: no mean-sub, no bias) -> bf16 ----------------
__global__ __launch_bounds__(256) void rmsnorm_kernel(const void* __restrict__ X,
                                                      const void* __restrict__ W,
                                                      u16* __restrict__ Out,
                                                      const int* __restrict__ flagp) {
  const int f32m = (*flagp == 0);
  __shared__ float part[4];
  const int tid = threadIdx.x, lane = tid & 63, wave = tid >> 6;
  const size_t row = blockIdx.x;
  const int c = tid * 4;
  float x0, x1, x2, x3, w0f, w1f, w2f, w3f;
  if (f32m) {
    const float4 xx = *(const float4*)((const float*)X + row * 1024 + c);
    x0 = xx.x; x1 = xx.y; x2 = xx.z; x3 = xx.w;
    const float4 ww = *(const float4*)((const float*)W + c);
    w0f = ww.x; w1f = ww.y; w2f = ww.z; w3f = ww.w;
  } else {
    const u32* px = (const u32*)((const u16*)X + row * 1024 + c);
    const u32 a0 = px[0], a1 = px[1];
    x0 = bf2f((u16)a0); x1 = bf2f((u16)(a0 >> 16));
    x2 = bf2f((u16)a1); x3 = bf2f((u16)(a1 >> 16));
    const u32* pw = (const u32*)((const u16*)W + c);
    const u32 b0 = pw[0], b1 = pw[1];
    w0f = bf2f((u16)b0); w1f = bf2f((u16)(b0 >> 16));
    w2f = bf2f((u16)b1); w3f = bf2f((u16)(b1 >> 16));
  }
  float ss = x0 * x0 + x1 * x1 + x2 * x2 + x3 * x3;
  #pragma unroll
  for (int off = 32; off >= 1; off >>= 1) ss += __shfl_xor(ss, off);
  if (lane == 0) part[wave] = ss;
  __syncthreads();
  const float tot = part[0] + part[1] + part[2] + part[3];
  const float scale = rsqrtf(tot * (1.0f / 1024.0f) + 1e-6f);
  const u16 o0 = f2bf(x0 * scale * w0f);
  const u16 o1 = f2bf(x1 * scale * w1f);
  const u16 o2 = f2bf(x2 * scale * w2f);
  const u16 o3 = f2bf(x3 * scale * w3f);
  u32* po = (u32*)(Out + row * 1024 + c);
  po[0] = (u32)o0 | ((u32)o1 << 16);
  po[1] = (u32)o2 | ((u32)o3 << 16);
}

// ------- shared 128x128x32 bf16 MFMA GEMM core (A[M][K], BT[N][K]) -------
// SWAP=false: acc[mt][nt] lane holds (s = m0+wm+mt*16+quad*4+r, n = n0+wn+nt*16+c)
// SWAP=true (operands swapped; frag reg layouts are identical):
//   lane holds (s = m0+wm+mt*16+c, n = n0+wn+nt*16+quad*4+r) -> 4 consecutive n
template <bool SWAP>
__device__ __forceinline__ void gemm_core(const u16* __restrict__ A, const u16* __restrict__ BT,
                                          u16* As, u16* Bs, f32x4 (&acc)[4][4],
                                          int m0, int n0, int K, int lane, int wave) {
  const int srow = lane >> 2, scol = (lane & 3) * 8;
  const int wm = (wave >> 1) * 64, wn = (wave & 1) * 64;
  for (int kt = 0; kt < K; kt += 32) {
    __syncthreads();
    #pragma unroll
    for (int i = 0; i < 2; ++i) {
      const int c = wave * 2 + i;
      async16(A + (size_t)(m0 + c * 16 + srow) * K + kt + scol, As + c * 512);
      async16(BT + (size_t)(n0 + c * 16 + srow) * K + kt + scol, Bs + c * 512);
    }
    __syncthreads();
    bf16x8 af[4], bfr[4];
    #pragma unroll
    for (int mt = 0; mt < 4; ++mt)
      af[mt] = *(const bf16x8*)(As + (wm + mt * 16 + (lane & 15)) * 32 + (lane >> 4) * 8);
    #pragma unroll
    for (int nt = 0; nt < 4; ++nt)
      bfr[nt] = *(const bf16x8*)(Bs + (wn + nt * 16 + (lane & 15)) * 32 + (lane >> 4) * 8);
    #pragma unroll
    for (int mt = 0; mt < 4; ++mt)
      #pragma unroll
      for (int nt = 0; nt < 4; ++nt) {
        if (SWAP)
          acc[mt][nt] = __builtin_amdgcn_mfma_f32_16x16x32_bf16(bfr[nt], af[mt], acc[mt][nt], 0, 0, 0);
        else
          acc[mt][nt] = __builtin_amdgcn_mfma_f32_16x16x32_bf16(af[mt], bfr[nt], acc[mt][nt], 0, 0, 0);
      }
  }
}

// ------- fused QKV projection GEMM: B = [WTq;WTk;WTv] = [3072][1024] -------
// XCD-aware swizzle: id = 8*(nb + 24*mhi) + (m&7) -> all 24 n-blocks sharing an
// A row-block run on one XCD (A enters each L2 once); weights are L3-resident.
__global__ __launch_bounds__(256) void qkv_gemm_kernel(
    const u16* __restrict__ A, const u16* __restrict__ WT,
    u16* __restrict__ Qo, u16* __restrict__ Ko, u16* __restrict__ Vo, int K) {
  __shared__ __align__(16) u16 As[128 * 32];
  __shared__ __align__(16) u16 Bs[128 * 32];
  const int tid = threadIdx.x, lane = tid & 63, wave = tid >> 6;
  const int id = blockIdx.x;
  const int xcd = id & 7;
  const int t = id >> 3;
  const int nb = t % 24;
  const int mhi = t / 24;
  const int m0 = (mhi * 8 + xcd) * 128;
  const int n0 = nb * 128;  // in [0,3072)
  const int z = nb >> 3;    // 0=Q 1=K 2=V

  f32x4 acc[4][4];
  const f32x4 zero = {0.f, 0.f, 0.f, 0.f};
  #pragma unroll
  for (int i = 0; i < 4; ++i)
    #pragma unroll
    for (int j = 0; j < 4; ++j) acc[i][j] = zero;

  const int wm = (wave >> 1) * 64, wn = (wave & 1) * 64;
  if (z == 2) {
    gemm_core<false>(A, WT, As, Bs, acc, m0, n0, K, lane, wave);
    // V^T layout: [b,h,dk,s]; lane holds 4 consecutive s for fixed (h,dk) -> b64 store
    #pragma unroll
    for (int mt = 0; mt < 4; ++mt) {
      const int mrow0 = m0 + wm + mt * 16 + (lane >> 4) * 4;
      const int b = mrow0 >> 10;
      const int s0 = mrow0 & 1023;
      #pragma unroll
      for (int nt = 0; nt < 4; ++nt) {
        const int n = (n0 + wn + nt * 16 + (lane & 15)) & 1023;
        const int hh = n >> 6, dk = n & 63;
        const u64 pk = (u64)f2bf(acc[mt][nt][0]) | ((u64)f2bf(acc[mt][nt][1]) << 16) |
                       ((u64)f2bf(acc[mt][nt][2]) << 32) | ((u64)f2bf(acc[mt][nt][3]) << 48);
        *(u64*)(Vo + (((size_t)(b * 16 + hh)) * 64 + dk) * 1024 + s0) = pk;
      }
    }
  } else {
    gemm_core<true>(A, WT, As, Bs, acc, m0, n0, K, lane, wave);
    u16* Out = (z == 0) ? Qo : Ko;
    // Q/K layout: [b,h,s,dk]; lane holds 4 consecutive dk for fixed s -> b64 store
    #pragma unroll
    for (int mt = 0; mt < 4; ++mt) {
      const int s = m0 + wm + mt * 16 + (lane & 15);
      const int b = s >> 10, ss = s & 1023;
      #pragma unroll
      for (int nt = 0; nt < 4; ++nt) {
        const int n = (n0 + wn + nt * 16 + (lane >> 4) * 4) & 1023;
        const int hh = n >> 6, dk = n & 63;
        const u64 pk = (u64)f2bf(acc[mt][nt][0]) | ((u64)f2bf(acc[mt][nt][1]) << 16) |
                       ((u64)f2bf(acc[mt][nt][2]) << 32) | ((u64)f2bf(acc[mt][nt][3]) << 48);
        *(u64*)(Out + (((size_t)(b * 16 + hh)) * 1024 + ss) * 64 + dk) = pk;
      }
    }
  }
}

// ---------------- output projection GEMM + residual; packed dtype-aware store ----------------
// Same XCD-aware swizzle: id = 8*(nb + 8*mhi) + (m&7)
__global__ __launch_bounds__(256) void out_gemm_kernel(
    const u16* __restrict__ A, const u16* __restrict__ BT, const void* __restrict__ Res,
    void* __restrict__ Out, int N, int K, const int* __restrict__ flagp) {
  const int f32m = (*flagp == 0);
  __shared__ __align__(16) u16 As[128 * 32];
  __shared__ __align__(16) u16 Bs[128 * 32];
  const int tid = threadIdx.x, lane = tid & 63, wave = tid >> 6;
  const int id = blockIdx.x;
  const int xcd = id & 7;
  const int t = id >> 3;
  const int nb = t & 7;
  const int mhi = t >> 3;
  const int m0 = (mhi * 8 + xcd) * 128;
  const int n0 = nb * 128;

  f32x4 acc[4][4];
  const f32x4 zero = {0.f, 0.f, 0.f, 0.f};
  #pragma unroll
  for (int i = 0; i < 4; ++i)
    #pragma unroll
    for (int j = 0; j < 4; ++j) acc[i][j] = zero;

  gemm_core<true>(A, BT, As, Bs, acc, m0, n0, K, lane, wave);

  const int wm = (wave >> 1) * 64, wn = (wave & 1) * 64;
  #pragma unroll
  for (int mt = 0; mt < 4; ++mt) {
    const int s = m0 + wm + mt * 16 + (lane & 15);
    #pragma unroll
    for (int nt = 0; nt < 4; ++nt) {
      const int n = n0 + wn + nt * 16 + (lane >> 4) * 4;
      const size_t idx = (size_t)s * N + n;
      if (f32m) {
        const float4 rr = *(const float4*)((const float*)Res + idx);
        float4 oo;
        oo.x = rr.x + acc[mt][nt][0]; oo.y = rr.y + acc[mt][nt][1];
        oo.z = rr.z + acc[mt][nt][2]; oo.w = rr.w + acc[mt][nt][3];
        *(float4*)((float*)Out + idx) = oo;
      } else {
        const u64 rr = *(const u64*)((const u16*)Res + idx);
        const u64 pk =
            (u64)f2bf(bf2f((u16)rr) + acc[mt][nt][0]) |
            ((u64)f2bf(bf2f((u16)(rr >> 16)) + acc[mt][nt][1]) << 16) |
            ((u64)f2bf(bf2f((u16)(rr >> 32)) + acc[mt][nt][2]) << 32) |
            ((u64)f2bf(bf2f((u16)(rr >> 48)) + acc[mt][nt][3]) << 48);
        *(u64*)((u16*)Out + idx) = pk;
      }
    }
  }
}

// -------- pipelined flash attention: dbuf LDS staging, LDS bias table, 32 q/wave --------
// Block = 128 q (4 waves x 32 q, complete rows -> no merge). K-tile = 64 k.
// K/V staged cooperatively via global_load_lds into double-buffered LDS (prefetch t+1
// issued right after the barrier). Bias slice Th[896-q0 .. 2046-q0] (1151 floats) loaded
// once into LDS -> the k-loop has NO global loads besides the 4 async16 staging ops.
// Scores transposed (S^T = K.Q^T, C-init = bias); P packs via v_perm into wave-private
// XOR-swizzled LDS, read back b128; out^T = V^T.P^T. Fixed-shift softmax (|s|<~55).
__global__ __launch_bounds__(256, 3) void attn_kernel(
    const u16* __restrict__ Q, const u16* __restrict__ K, const u16* __restrict__ VT,
    const float* __restrict__ Tb, u16* __restrict__ ctx) {
  __shared__ __align__(16) u16 Ks[2][4096];  // [buf][8 groups x 512] (mt,half)
  __shared__ __align__(16) u16 Vs[2][4096];  // [buf][8 groups x 512] (dt,kk)
  __shared__ __align__(16) u16 Ps[4][2048];  // wave-private [32 q][64 k] swizzled
  __shared__ __align__(16) float Tbs[1152];  // block bias slice

  const int tid = threadIdx.x, lane = tid & 63, w = tid >> 6;
  const int c = lane & 15, quad = lane >> 4;
  const int id = blockIdx.x;
  const int bh = id & 127, qc = id >> 7;  // same-bh blocks -> same XCD (id%8 == bh%8)
  const int b = bh >> 4, h = bh & 15;
  const int q0 = qc * 128;
  const int qw = q0 + w * 32;  // wave's first q row
  const u16* Kg = K + (size_t)bh * 1024 * 64;
  const u16* Vg = VT + (size_t)bh * 64 * 1024;
  const float* Th = Tb + h * 2047;
  u16* PsW = &Ps[w][0];

  // one-time cooperative bias-slice load (indices 896-q0 .. 2047-q0; last never read)
  #pragma unroll
  for (int i = tid; i < 1152; i += 256) Tbs[i] = Th[896 - q0 + i];

  // hoisted Q^T B-frags: q = qw + nt*16 + c ; k-elems dk = half*32 + quad*8
  bf16x8 qf[2][2];
  {
    const u16* Qg = Q + ((size_t)bh * 1024 + qw) * 64;
    #pragma unroll
    for (int nt = 0; nt < 2; ++nt)
      #pragma unroll
      for (int half = 0; half < 2; ++half)
        qf[nt][half] = *(const bf16x8*)(Qg + (size_t)(nt * 16 + c) * 64 + half * 32 + quad * 8);
  }

  f32x4 oacc[4][2];
  const f32x4 zero = {0.f, 0.f, 0.f, 0.f};
  #pragma unroll
  for (int i = 0; i < 4; ++i)
    #pragma unroll
    for (int j = 0; j < 2; ++j) oacc[i][j] = zero;
  float rsum[2] = {0.f, 0.f};

  // cooperative staging: wave w stages K rows mt=w (both halves) and V rows dt=w
  {
    const int k0 = 0;
    #pragma unroll
    for (int i = 0; i < 2; ++i) {
      async16(Kg + (size_t)(k0 + w * 16 + c) * 64 + i * 32 + quad * 8, &Ks[0][(w * 2 + i) * 512]);
      async16(Vg + (size_t)(w * 16 + c) * 1024 + k0 + i * 32 + quad * 8, &Vs[0][(w * 2 + i) * 512]);
    }
  }

  #pragma unroll 1
  for (int kt = 0; kt < 16; ++kt) {
    const int cur = kt & 1;
    __asm__ volatile("s_waitcnt vmcnt(0)" ::: "memory");  // tile kt staged
    __syncthreads();
    if (kt < 15) {  // stage tile kt+1 into the other buffer (overlaps this iter's compute)
      const int k1 = (kt + 1) * 64;
      #pragma unroll
      for (int i = 0; i < 2; ++i) {
        async16(Kg + (size_t)(k1 + w * 16 + c) * 64 + i * 32 + quad * 8,
                &Ks[1 - cur][(w * 2 + i) * 512]);
        async16(Vg + (size_t)(w * 16 + c) * 1024 + k1 + i * 32 + quad * 8,
                &Vs[1 - cur][(w * 2 + i) * 512]);
      }
    }
    const int k0 = kt * 64;
    // bias into MFMA C operand from the LDS slice:
    //   Tbs[j] = Th[j + 896 - q0]; needed Th[k - q + 1023] -> j = k0+16mt+4quad+r - c + 127 - 32w - 16nt
    f32x4 sc[4][2];
    const int jb = k0 + quad * 4 - c + 127 - 32 * w;
    #pragma unroll
    for (int mt = 0; mt < 4; ++mt)
      #pragma unroll
      for (int nt = 0; nt < 2; ++nt) {
        const float* tp = Tbs + jb + mt * 16 - nt * 16;
        sc[mt][nt][0] = tp[0]; sc[mt][nt][1] = tp[1]; sc[mt][nt][2] = tp[2]; sc[mt][nt][3] = tp[3];
      }
    // S^T = K.Q^T
    const u16* Kc = &Ks[cur][0];
    #pragma unroll
    for (int mt = 0; mt < 4; ++mt) {
      const bf16x8 kf0 = *(const bf16x8*)(Kc + (mt * 2 + 0) * 512 + lane * 8);
      const bf16x8 kf1 = *(const bf16x8*)(Kc + (mt * 2 + 1) * 512 + lane * 8);
      #pragma unroll
      for (int nt = 0; nt < 2; ++nt) {
        sc[mt][nt] = __builtin_amdgcn_mfma_f32_16x16x32_bf16(kf0, qf[nt][0], sc[mt][nt], 0, 0, 0);
        sc[mt][nt] = __builtin_amdgcn_mfma_f32_16x16x32_bf16(kf1, qf[nt][1], sc[mt][nt], 0, 0, 0);
      }
    }
    // exp -> rsum partial -> v_perm pack 4 consecutive k as one b64 swizzled LDS write
    #pragma unroll
    for (int mt = 0; mt < 4; ++mt)
      #pragma unroll
      for (int nt = 0; nt < 2; ++nt) {
        const float p0 = __expf(sc[mt][nt][0]), p1 = __expf(sc[mt][nt][1]);
        const float p2 = __expf(sc[mt][nt][2]), p3 = __expf(sc[mt][nt][3]);
        rsum[nt] += (p0 + p1) + (p2 + p3);
        const u32 lo = pkbf(p0, p1), hi = pkbf(p2, p3);
        const u64 pk = (u64)lo | ((u64)hi << 32);
        const int ch = (mt * 2 + (quad >> 1)) ^ (c & 7);
        *(u64*)(PsW + (nt * 16 + c) * 64 + ch * 8 + (quad & 1) * 4) = pk;
      }
    __asm__ volatile("s_waitcnt lgkmcnt(0)" ::: "memory");  // own P writes visible
    // out^T += V^T . P^T
    const u16* Vc = &Vs[cur][0];
    bf16x8 pf[2][2];
    #pragma unroll
    for (int nt = 0; nt < 2; ++nt)
      #pragma unroll
      for (int kk = 0; kk < 2; ++kk) {
        const int ch = (kk * 4 + quad) ^ (c & 7);
        pf[nt][kk] = *(const bf16x8*)(PsW + (nt * 16 + c) * 64 + ch * 8);
      }
    #pragma unroll
    for (int dt = 0; dt < 4; ++dt) {
      const bf16x8 vf0 = *(const bf16x8*)(Vc + (dt * 2 + 0) * 512 + lane * 8);
      const bf16x8 vf1 = *(const bf16x8*)(Vc + (dt * 2 + 1) * 512 + lane * 8);
      #pragma unroll
      for (int nt = 0; nt < 2; ++nt) {
        oacc[dt][nt] = __builtin_amdgcn_mfma_f32_16x16x32_bf16(vf0, pf[nt][0], oacc[dt][nt], 0, 0, 0);
        oacc[dt][nt] = __builtin_amdgcn_mfma_f32_16x16x32_bf16(vf1, pf[nt][1], oacc[dt][nt], 0, 0, 0);
      }
    }
  }

  // fold quads: lanes (c, c+16, c+32, c+48) hold disjoint k-partitions of q-row c
  #pragma unroll
  for (int nt = 0; nt < 2; ++nt) {
    rsum[nt] += __shfl_xor(rsum[nt], 16);
    rsum[nt] += __shfl_xor(rsum[nt], 32);
  }

  #pragma unroll
  for (int nt = 0; nt < 2; ++nt) {
    const float inv = 1.0f / rsum[nt];
    const int q = qw + nt * 16 + c;
    #pragma unroll
    for (int dt = 0; dt < 4; ++dt) {
      const u64 pk = (u64)f2bf(oacc[dt][nt][0] * inv) | ((u64)f2bf(oacc[dt][nt][1] * inv) << 16) |
                     ((u64)f2bf(oacc[dt][nt][2] * inv) << 32) | ((u64)f2bf(oacc[dt][nt][3] * inv) << 48);
      // ctx layout: [b, s, h, dk]; lane holds 4 consecutive dk = dt*16 + quad*4 + r
      *(u64*)(ctx + (((size_t)b * 1024 + q) * 16 + h) * 64 + dt * 16 + quad * 4) = pk;
    }
  }
}

extern "C" void kernel_launch(void* const* d_in, const int* in_sizes, int n_in,
                              void* d_out, int out_size, void* d_ws, size_t ws_size,
                              hipStream_t stream) {
  const void* hidden = d_in[0];
  const void* lnw = d_in[1];
  const void* wq = d_in[2];
  const void* wk = d_in[3];
  const void* wv = d_in[4];
  const void* wo = d_in[5];
  const void* relb = d_in[6];
  char* ws = (char*)d_ws;

  u16* normed = (u16*)(ws);                        // 16 MB; reused as ctx after QKV
  u16* Qb = (u16*)(ws + ((size_t)16 << 20));       // 16 MB
  u16* Kb = (u16*)(ws + ((size_t)32 << 20));       // 16 MB
  u16* VTb = (u16*)(ws + ((size_t)48 << 20));      // 16 MB
  u16* wtq = (u16*)(ws + ((size_t)64 << 20));      // [3072][1024] fused B: wtq|wtk|wtv
  u16* wtk = (u16*)(ws + ((size_t)64 << 20) + (2 << 20));
  u16* wtv = (u16*)(ws + ((size_t)64 << 20) + (4 << 20));
  u16* wto = (u16*)(ws + ((size_t)64 << 20) + (6 << 20));
  float* Tb = (float*)(ws + ((size_t)64 << 20) + (8 << 20));  // 131 KB
  int* flag = (int*)(ws + ((size_t)64 << 20) + (9 << 20));

  dim3 b256(256);
  detect_kernel<<<dim3(1), b256, 0, stream>>>((const u32*)hidden, flag);
  prep_kernel<<<dim3(16, 16, 5), b256, 0, stream>>>(wq, wk, wv, wo, wtq, wtk, wtv, wto,
                                                    relb, Tb, flag);
  rmsnorm_kernel<<<dim3(8192), b256, 0, stream>>>(hidden, lnw, normed, flag);
  qkv_gemm_kernel<<<dim3(1536), b256, 0, stream>>>(normed, wtq, Qb, Kb, VTb, 1024);
  attn_kernel<<<dim3(1024), b256, 0, stream>>>(Qb, Kb, VTb, Tb, normed);
  out_gemm_kernel<<<dim3(512), b256, 0, stream>>>(normed, wto, hidden, d_out, 1024, 1024, flag);
}